// Round 1
// baseline (2739.276 us; speedup 1.0000x reference)
//
#include <hip/hip_runtime.h>

#define NB    2
#define BTOK  8192
#define DDIM  1024
#define HDIM  1024
#define NEXP  8
#define NQ    8
#define NL    2

// ---------------------------------------------------------------------------
// Gate: logits = x@gW + gb, softmax, top-2 (jax tie-break = lowest index),
// weights = softmax over the two top PROBABILITIES (reference semantics).
// Also initializes yacc = x (residual accumulator) while x is in registers.
// ---------------------------------------------------------------------------
__global__ __launch_bounds__(256) void k_gate(
    const float* __restrict__ xin, const float* __restrict__ gW,
    const float* __restrict__ gb, float* __restrict__ selw,
    int* __restrict__ cnt, int* __restrict__ list, float* __restrict__ yacc) {
  __shared__ float sgw[NEXP][DDIM];   // transposed gate weights, 32KB
  int tid = threadIdx.x;
  for (int i = tid; i < DDIM * NEXP; i += 256)
    sgw[i & 7][i >> 3] = gW[i];
  __syncthreads();

  int wave = tid >> 6, lane = tid & 63;
  int t = blockIdx.x * 4 + wave;
  const float4* xr = (const float4*)(xin + (size_t)t * DDIM);
  float4* yw = (float4*)(yacc + (size_t)t * DDIM);

  float acc[NEXP] = {0.f,0.f,0.f,0.f,0.f,0.f,0.f,0.f};
  #pragma unroll
  for (int c = 0; c < 4; ++c) {
    int f4 = c * 64 + lane;
    float4 xv = xr[f4];
    yw[f4] = xv;                      // yacc = x
    int d0 = f4 * 4;
    #pragma unroll
    for (int e = 0; e < NEXP; ++e) {
      float4 gv = *(const float4*)&sgw[e][d0];
      acc[e] += xv.x*gv.x + xv.y*gv.y + xv.z*gv.z + xv.w*gv.w;
    }
  }
  #pragma unroll
  for (int e = 0; e < NEXP; ++e) {
    float v = acc[e];
    #pragma unroll
    for (int off = 32; off; off >>= 1) v += __shfl_xor(v, off);
    acc[e] = v;
  }

  if (lane == 0) {
    float p[NEXP];
    float m = -3.4e38f;
    #pragma unroll
    for (int e = 0; e < NEXP; ++e) { p[e] = acc[e] + gb[e]; m = fmaxf(m, p[e]); }
    float s = 0.f;
    #pragma unroll
    for (int e = 0; e < NEXP; ++e) { p[e] = expf(p[e] - m); s += p[e]; }
    float inv = 1.f / s;
    #pragma unroll
    for (int e = 0; e < NEXP; ++e) p[e] *= inv;
    // top-2 with lowest-index tie-break (strict >)
    int i1 = 0;
    #pragma unroll
    for (int e = 1; e < NEXP; ++e) if (p[e] > p[i1]) i1 = e;
    int i2 = (i1 == 0) ? 1 : 0;
    #pragma unroll
    for (int e = 0; e < NEXP; ++e)
      if (e != i1 && e != i2 && p[e] > p[i2]) i2 = e;
    float pa = p[i1], pb = p[i2];
    // softmax over the two top probabilities
    float eb = expf(pb - pa);
    float wa = 1.f / (1.f + eb);
    float wb = eb * wa;
    int t2 = t * 2;
    selw[t2]   = wa;
    selw[t2+1] = wb;
    int pos1 = atomicAdd(&cnt[i1], 1);
    list[i1 * BTOK + pos1] = t2;
    int pos2 = atomicAdd(&cnt[i2], 1);
    list[i2 * BTOK + pos2] = t2 + 1;
  }
}

// ---------------------------------------------------------------------------
// Quantum sim per selected (token, expert).
// Math: initial state = product ⊗[cos(a/2), sin(a/2)]; first Rot layer is
// ⊗ of per-qubit 2x2 gates -> rotate each 2-vector first (still product).
// CNOT chains are basis permutations j = prefix-XOR(i) (qubit0 = MSB):
// chain 1 folded into the product-state scatter, chain 2 folded into Z signs.
// Only layer-2's 8 Rot gates need full 128-pair state updates.
// One token-expert per thread, state column-per-thread in LDS (no conflicts,
// no barriers). 64 threads * 256 complex amps * fp32 = 128KB + 8KB scratch.
// ---------------------------------------------------------------------------
__device__ __forceinline__ int pfx(int i) {
  int j = i ^ (i >> 1); j ^= (j >> 2); j ^= (j >> 4); return j;
}

__global__ __launch_bounds__(64) void k_qsim(
    const float* __restrict__ xin, const float* __restrict__ qp,
    const int* __restrict__ list, const int* __restrict__ cnt,
    float* __restrict__ q8) {
  extern __shared__ float sm[];
  float* sre  = sm;            // 16384 floats
  float* simg = sm + 16384;    // 16384 floats
  float* tTr  = sm + 32768;    // 1024 floats
  float* tTi  = sm + 33792;    // 1024 floats

  int e = blockIdx.y;
  int pos = blockIdx.x * 64 + threadIdx.x;
  if (pos >= cnt[e]) return;
  int tid = threadIdx.x;
  int t = list[e * BTOK + pos] >> 1;

  // layer-0 rotated per-qubit 2-vectors: v = Rot(phi,th,om) @ [cos(a/2), sin(a/2)]
  float v0r[NQ], v0i[NQ], v1r[NQ], v1i[NQ];
  const float* qp0 = qp + (size_t)e * NL * NQ * 3;
  #pragma unroll
  for (int q = 0; q < NQ; ++q) {
    float a   = xin[(size_t)t * DDIM + q];
    float phi = qp0[q*3+0], th = qp0[q*3+1], om = qp0[q*3+2];
    float sa, ca;  sincosf(0.5f * a, &sa, &ca);
    float s,  c;   sincosf(0.5f * th, &s, &c);
    float sp, cp;  sincosf(0.5f * (phi + om), &sp, &cp);
    float sq_, cq_; sincosf(0.5f * (phi - om), &sq_, &cq_);
    // M00=c(cp,-sp) M01=-s(cq,sq) M10=s(cq,-sq) M11=c(cp,sp)
    v0r[q] =  c*cp*ca - s*cq_*sa;
    v0i[q] = -c*sp*ca - s*sq_*sa;
    v1r[q] =  s*cq_*ca + c*cp*sa;
    v1i[q] = -s*sq_*ca + c*sp*sa;
  }

  // product over qubits 0..3 (R) and 4..7 (T), fully unrolled in registers
  float Rr[16], Ri[16], Tr[16], Ti[16];
  Rr[0]=v0r[0]; Ri[0]=v0i[0]; Rr[1]=v1r[0]; Ri[1]=v1i[0];
  Tr[0]=v0r[4]; Ti[0]=v0i[4]; Tr[1]=v1r[4]; Ti[1]=v1i[4];
  #pragma unroll
  for (int q = 1; q < 4; ++q) {
    #pragma unroll
    for (int i = (1<<q)-1; i >= 0; --i) {
      float xr_ = Rr[i], xi_ = Ri[i];
      Rr[2*i+1] = xr_*v1r[q]   - xi_*v1i[q];
      Ri[2*i+1] = xr_*v1i[q]   + xi_*v1r[q];
      Rr[2*i]   = xr_*v0r[q]   - xi_*v0i[q];
      Ri[2*i]   = xr_*v0i[q]   + xi_*v0r[q];
      float yr_ = Tr[i], yi_ = Ti[i];
      Tr[2*i+1] = yr_*v1r[q+4] - yi_*v1i[q+4];
      Ti[2*i+1] = yr_*v1i[q+4] + yi_*v1r[q+4];
      Tr[2*i]   = yr_*v0r[q+4] - yi_*v0i[q+4];
      Ti[2*i]   = yr_*v0i[q+4] + yi_*v0r[q+4];
    }
  }
  #pragma unroll
  for (int i = 0; i < 16; ++i) { tTr[i*64+tid] = Tr[i]; tTi[i*64+tid] = Ti[i]; }

  // psi[perm1(hi*16+lo)] = R[hi]*T[lo]   (CNOT chain 1 folded into scatter)
  #pragma unroll
  for (int hi = 0; hi < 16; ++hi) {
    float rr = Rr[hi], ri = Ri[hi];
    for (int lo = 0; lo < 16; ++lo) {
      float tr = tTr[lo*64+tid], ti = tTi[lo*64+tid];
      int j = pfx(hi*16 + lo);           // uniform scalar math
      sre [j*64+tid] = rr*tr - ri*ti;
      simg[j*64+tid] = rr*ti + ri*tr;
    }
  }

  // layer-1 Rot gates: full 1q gate on qubit q (index bit 7-q)
  const float* qp1 = qp0 + NQ*3;
  for (int q = 0; q < NQ; ++q) {
    float phi = qp1[q*3+0], th = qp1[q*3+1], om = qp1[q*3+2];
    float s,  c;   sincosf(0.5f * th, &s, &c);
    float sp, cp;  sincosf(0.5f * (phi + om), &sp, &cp);
    float sq_, cq_; sincosf(0.5f * (phi - om), &sq_, &cq_);
    float M00r =  c*cp,  M00i = -c*sp;
    float M01r = -s*cq_, M01i = -s*sq_;
    float M10r =  s*cq_, M10i = -s*sq_;
    float M11r =  c*cp,  M11i =  c*sp;
    int bm = 1 << (7 - q);
    int lowm = bm - 1;
    #pragma unroll 8
    for (int pp = 0; pp < 128; ++pp) {
      int i0 = ((pp & ~lowm) << 1) | (pp & lowm);
      int i1 = i0 | bm;
      int o0 = i0*64+tid, o1 = i1*64+tid;
      float a0r = sre[o0], a0i = simg[o0];
      float a1r = sre[o1], a1i = simg[o1];
      sre [o0] = M00r*a0r - M00i*a0i + M01r*a1r - M01i*a1i;
      simg[o0] = M00r*a0i + M00i*a0r + M01r*a1i + M01i*a1r;
      sre [o1] = M10r*a0r - M10i*a0i + M11r*a1r - M11i*a1i;
      simg[o1] = M10r*a0i + M10i*a0r + M11r*a1i + M11i*a1r;
    }
  }

  // readout: z[q'] = sum_i |psi_i|^2 * sign(bit 7-q' of perm2(i))
  float z[NQ] = {0.f,0.f,0.f,0.f,0.f,0.f,0.f,0.f};
  for (int i = 0; i < 256; ++i) {
    int o = i*64+tid;
    float rr = sre[o], ii = simg[o];
    float pb = rr*rr + ii*ii;
    int j = pfx(i);
    #pragma unroll
    for (int q = 0; q < NQ; ++q)
      z[q] += ((j >> (7 - q)) & 1) ? -pb : pb;
  }
  float* dst = q8 + (size_t)(e * BTOK + pos) * 8;
  #pragma unroll
  for (int q = 0; q < NQ; ++q) dst[q] = z[q];
}

// ---------------------------------------------------------------------------
// Fused expert MLP (fp32, selected rows only):
//   out = relu(q8 @ rW + rb) @ w2 + b2 ;  yacc[token] += w * out (atomic)
// Tile 128x128, K-chunk 32, 256 threads, 8x8 acc per thread.
// h-tile recomputed from the 8-wide q each chunk (cheap).
// Grid.x = (e,ct) strip id so consecutive raw ids = different strips ->
// each strip's 16 row-tiles land on one XCD (raw%8) -> w2 strip stays in L2.
// ---------------------------------------------------------------------------
#define TM 128
#define TN 128
#define TK 32

__global__ __launch_bounds__(256) void k_mlp(
    const float* __restrict__ q8, const float* __restrict__ rW,
    const float* __restrict__ rb, const float* __restrict__ w2,
    const float* __restrict__ b2, const int* __restrict__ list,
    const int* __restrict__ cnt, const float* __restrict__ selw,
    float* __restrict__ yacc) {
  int ex = blockIdx.x;
  int e = ex >> 3, ct = ex & 7, rt = blockIdx.y;
  int n = cnt[e];
  int r0 = rt * TM;
  if (r0 >= n) return;
  int tid = threadIdx.x;
  const float* rWe = rW + (size_t)e * NQ * HDIM;
  const float* rbe = rb + (size_t)e * HDIM;
  const float* w2e = w2 + (size_t)e * HDIM * DDIM;
  const float* b2e = b2 + (size_t)e * DDIM;

  __shared__ float sq8[TM][9];       // +1 pad: conflict-free strided reads
  __shared__ int   sent[TM];
  __shared__ float hT[TK][TM];       // h transposed for b128 A-frag reads
  __shared__ float sB[TK][TN];
  __shared__ float srW[8][TK];

  for (int i = tid; i < TM; i += 256)
    sent[i] = list[e * BTOK + ((r0 + i < n) ? (r0 + i) : r0)];
  for (int i = tid; i < TM*8; i += 256) {
    int rr = i >> 3, j = i & 7;
    sq8[rr][j] = (r0 + rr < n) ? q8[(size_t)(e * BTOK + r0 + rr) * 8 + j] : 0.f;
  }

  float acc[8][8];
  #pragma unroll
  for (int u = 0; u < 8; ++u)
    #pragma unroll
    for (int v = 0; v < 8; ++v) acc[u][v] = 0.f;

  int ty = tid >> 4, tx = tid & 15;

  for (int kh = 0; kh < HDIM / TK; ++kh) {
    __syncthreads();   // previous-iter LDS reads done before restaging
    {  // stage rW chunk (8 x TK) -- exactly 256 elements
      int j = tid >> 5, kk = tid & 31;
      srW[j][kk] = rWe[j * HDIM + kh * TK + kk];
    }
    #pragma unroll
    for (int i = 0; i < (TK*TN)/(256*4); ++i) {   // stage w2 chunk (TK x TN)
      int v = tid + 256*i;
      int kk = v >> 5, c4 = v & 31;
      *(float4*)&sB[kk][c4*4] =
        *(const float4*)&w2e[(size_t)(kh*TK + kk) * DDIM + ct*TN + c4*4];
    }
    __syncthreads();
    #pragma unroll
    for (int i = 0; i < (TM*TK)/256; ++i) {       // hT = relu(q8@rW + rb)^T
      int v = tid + 256*i;
      int r = v & (TM-1), kk = v >> 7;
      float hv = rbe[kh*TK + kk];
      #pragma unroll
      for (int j = 0; j < 8; ++j) hv += sq8[r][j] * srW[j][kk];
      hT[kk][r] = fmaxf(hv, 0.f);
    }
    __syncthreads();
    #pragma unroll
    for (int kk = 0; kk < TK; ++kk) {
      float a0[4], a1[4], b0[4], b1[4];
      *(float4*)a0 = *(const float4*)&hT[kk][ty*8];
      *(float4*)a1 = *(const float4*)&hT[kk][ty*8+4];
      *(float4*)b0 = *(const float4*)&sB[kk][tx*8];
      *(float4*)b1 = *(const float4*)&sB[kk][tx*8+4];
      #pragma unroll
      for (int u = 0; u < 4; ++u)
        #pragma unroll
        for (int v = 0; v < 4; ++v) {
          acc[u][v]     += a0[u]*b0[v];
          acc[u][v+4]   += a0[u]*b1[v];
          acc[u+4][v]   += a1[u]*b0[v];
          acc[u+4][v+4] += a1[u]*b1[v];
        }
    }
  }

  #pragma unroll
  for (int u = 0; u < 8; ++u) {
    int rr = ty*8 + u;
    if (r0 + rr < n) {
      int ent = sent[rr];
      int t = ent >> 1;
      float w = selw[ent];
      float* dst = yacc + (size_t)t * DDIM + ct*TN + tx*8;
      #pragma unroll
      for (int v = 0; v < 8; ++v) {
        float val = (acc[u][v] + b2e[ct*TN + tx*8 + v]) * w;
        atomicAdd(&dst[v], val);
      }
    }
  }
}

// ---------------------------------------------------------------------------
// LayerNorm over the accumulated residual stream (two-pass, matches ref).
// ---------------------------------------------------------------------------
__global__ __launch_bounds__(256) void k_ln(
    const float* __restrict__ yacc, const float* __restrict__ g,
    const float* __restrict__ bta, float* __restrict__ out) {
  int t = blockIdx.x, tid = threadIdx.x;
  const float4* yr = (const float4*)(yacc + (size_t)t * DDIM);
  float4 y = yr[tid];
  float s = y.x + y.y + y.z + y.w;
  #pragma unroll
  for (int off = 32; off; off >>= 1) s += __shfl_xor(s, off);
  __shared__ float red1[4], red2[4];
  int wave = tid >> 6, lane = tid & 63;
  if (lane == 0) red1[wave] = s;
  __syncthreads();
  float mu = (red1[0]+red1[1]+red1[2]+red1[3]) * (1.f/(float)DDIM);
  float ax = y.x - mu, ay = y.y - mu, az = y.z - mu, aw = y.w - mu;
  float sq = ax*ax + ay*ay + az*az + aw*aw;
  #pragma unroll
  for (int off = 32; off; off >>= 1) sq += __shfl_xor(sq, off);
  if (lane == 0) red2[wave] = sq;
  __syncthreads();
  float var = (red2[0]+red2[1]+red2[2]+red2[3]) * (1.f/(float)DDIM);
  float rs = 1.f / sqrtf(var + 1e-5f);
  float4 gv = ((const float4*)g)[tid];
  float4 bv = ((const float4*)bta)[tid];
  float4 o;
  o.x = ax*rs*gv.x + bv.x;
  o.y = ay*rs*gv.y + bv.y;
  o.z = az*rs*gv.z + bv.z;
  o.w = aw*rs*gv.w + bv.w;
  ((float4*)(out + (size_t)t * DDIM))[tid] = o;
}

// ---------------------------------------------------------------------------
extern "C" void kernel_launch(void* const* d_in, const int* in_sizes, int n_in,
                              void* d_out, int out_size, void* d_ws, size_t ws_size,
                              hipStream_t stream) {
  const float* x   = (const float*)d_in[0];
  const float* gW  = (const float*)d_in[1];   // (NB, D, E)
  const float* gb  = (const float*)d_in[2];   // (NB, E)
  const float* qp  = (const float*)d_in[3];   // (NB, E, NL, NQ, 3)
  const float* rW  = (const float*)d_in[4];   // (NB, E, NQ, H)
  const float* rb  = (const float*)d_in[5];   // (NB, E, H)
  const float* w2  = (const float*)d_in[6];   // (NB, E, H, D)
  const float* b2  = (const float*)d_in[7];   // (NB, E, D)
  const float* lg  = (const float*)d_in[8];   // (NB, D)
  const float* lb  = (const float*)d_in[9];   // (NB, D)
  float* out = (float*)d_out;

  char* ws = (char*)d_ws;
  float* yacc = (float*)ws;                           // 32 MB
  float* q8   = (float*)(ws + (size_t)33554432);      // 2 MB
  float* selw = (float*)(ws + (size_t)35651584);      // 64 KB
  int*   list = (int*)  (ws + (size_t)35717120);      // 256 KB
  int*   cnt  = (int*)  (ws + (size_t)35979264);      // 32 B

  // allow 136KB dynamic LDS for k_qsim (idempotent, cheap, not captured)
  hipFuncSetAttribute(reinterpret_cast<const void*>(k_qsim),
      hipFuncAttributeMaxDynamicSharedMemorySize, 139264);

  for (int blk = 0; blk < NB; ++blk) {
    const float* xin = blk ? (const float*)out : x;
    hipMemsetAsync(cnt, 0, NEXP * sizeof(int), stream);
    k_gate<<<dim3(BTOK/4), 256, 0, stream>>>(
        xin, gW + (size_t)blk * DDIM * NEXP, gb + (size_t)blk * NEXP,
        selw, cnt, list, yacc);
    k_qsim<<<dim3(BTOK/64, NEXP), 64, 139264, stream>>>(
        xin, qp + (size_t)blk * NEXP * NL * NQ * 3, list, cnt, q8);
    k_mlp<<<dim3(64, 64), 256, 0, stream>>>(
        q8, rW + (size_t)blk * NEXP * NQ * HDIM, rb + (size_t)blk * NEXP * HDIM,
        w2 + (size_t)blk * NEXP * HDIM * DDIM, b2 + (size_t)blk * NEXP * DDIM,
        list, cnt, selw, yacc);
    k_ln<<<dim3(BTOK), 256, 0, stream>>>(
        yacc, lg + (size_t)blk * DDIM, lb + (size_t)blk * DDIM, out);
  }
}

// Round 2
// 1646.289 us; speedup vs baseline: 1.6639x; 1.6639x over previous
//
#include <hip/hip_runtime.h>
#include <hip/hip_bf16.h>

#define NB    2
#define BTOK  8192
#define DDIM  1024
#define HDIM  1024
#define NEXP  8
#define NQ    8
#define NL    2

typedef __attribute__((ext_vector_type(8))) short short8;
typedef __attribute__((ext_vector_type(4))) float f32x4;

__device__ __forceinline__ unsigned short f2bf(float v) {
  union { __hip_bfloat16 b; unsigned short u; } cv;
  cv.b = __float2bfloat16(v);
  return cv.u;
}
__device__ __forceinline__ float bf2f(unsigned short u) {
  union { unsigned short u; __hip_bfloat16 b; } cv;
  cv.u = u;
  return __bfloat162float(cv.b);
}

__device__ __forceinline__ void gload_lds16(const void* g, void* l) {
  __builtin_amdgcn_global_load_lds(
      (const __attribute__((address_space(1))) unsigned int*)g,
      (__attribute__((address_space(3))) unsigned int*)l, 16, 0, 0);
}

// ---------------------------------------------------------------------------
// Gate: logits = x@gW + gb, softmax, top-2 (strict > = lowest-index ties),
// weights = softmax over the two top PROBS. Seeds yacc(=d_out) with x.
// Writes slot-0 (top-1) and slot-1 (top-2) entry lists separately so the
// GEMM epilogue can do non-atomic read-modify-write on yacc.
// ---------------------------------------------------------------------------
__global__ __launch_bounds__(256) void k_gate(
    const float* __restrict__ xin, const float* __restrict__ gW,
    const float* __restrict__ gb, float* __restrict__ selw,
    int* __restrict__ cntA, int* __restrict__ cntB,
    int* __restrict__ listA, int* __restrict__ listB,
    float* __restrict__ yacc) {
  __shared__ float sgw[NEXP][DDIM];   // transposed gate weights, 32KB
  int tid = threadIdx.x;
  for (int i = tid; i < DDIM * NEXP; i += 256)
    sgw[i & 7][i >> 3] = gW[i];
  __syncthreads();

  int wave = tid >> 6, lane = tid & 63;
  int t = blockIdx.x * 4 + wave;
  const float4* xr = (const float4*)(xin + (size_t)t * DDIM);
  float4* yw = (float4*)(yacc + (size_t)t * DDIM);

  float acc[NEXP] = {0.f,0.f,0.f,0.f,0.f,0.f,0.f,0.f};
  #pragma unroll
  for (int c = 0; c < 4; ++c) {
    int f4 = c * 64 + lane;
    float4 xv = xr[f4];
    yw[f4] = xv;                      // yacc = x
    int d0 = f4 * 4;
    #pragma unroll
    for (int e = 0; e < NEXP; ++e) {
      float4 gv = *(const float4*)&sgw[e][d0];
      acc[e] += xv.x*gv.x + xv.y*gv.y + xv.z*gv.z + xv.w*gv.w;
    }
  }
  #pragma unroll
  for (int e = 0; e < NEXP; ++e) {
    float v = acc[e];
    #pragma unroll
    for (int off = 32; off; off >>= 1) v += __shfl_xor(v, off);
    acc[e] = v;
  }

  if (lane == 0) {
    float p[NEXP];
    float m = -3.4e38f;
    #pragma unroll
    for (int e = 0; e < NEXP; ++e) { p[e] = acc[e] + gb[e]; m = fmaxf(m, p[e]); }
    float s = 0.f;
    #pragma unroll
    for (int e = 0; e < NEXP; ++e) { p[e] = expf(p[e] - m); s += p[e]; }
    float inv = 1.f / s;
    #pragma unroll
    for (int e = 0; e < NEXP; ++e) p[e] *= inv;
    int i1 = 0;
    #pragma unroll
    for (int e = 1; e < NEXP; ++e) if (p[e] > p[i1]) i1 = e;
    int i2 = (i1 == 0) ? 1 : 0;
    #pragma unroll
    for (int e = 0; e < NEXP; ++e)
      if (e != i1 && e != i2 && p[e] > p[i2]) i2 = e;
    float pa = p[i1], pb = p[i2];
    float eb = expf(pb - pa);
    float wa = 1.f / (1.f + eb);
    float wb = eb * wa;
    int t2 = t * 2;
    selw[t2]   = wa;
    selw[t2+1] = wb;
    int pos1 = atomicAdd(&cntA[i1], 1);
    listA[i1 * BTOK + pos1] = t2;
    int pos2 = atomicAdd(&cntB[i2], 1);
    listB[i2 * BTOK + pos2] = t2 + 1;
  }
}

// ---------------------------------------------------------------------------
// Quantum sim per selected (token, expert). Unchanged math from round 1
// (verified correct); indexing switched to slot-split lists + ent-indexed q8.
// ---------------------------------------------------------------------------
__device__ __forceinline__ int pfx(int i) {
  int j = i ^ (i >> 1); j ^= (j >> 2); j ^= (j >> 4); return j;
}

__global__ __launch_bounds__(64) void k_qsim(
    const float* __restrict__ xin, const float* __restrict__ qp,
    const int* __restrict__ listA, const int* __restrict__ listB,
    const int* __restrict__ cntA, const int* __restrict__ cntB,
    float* __restrict__ q8) {
  extern __shared__ float sm[];
  float* sre  = sm;            // 16384 floats
  float* simg = sm + 16384;    // 16384 floats
  float* tTr  = sm + 32768;    // 1024 floats
  float* tTi  = sm + 33792;    // 1024 floats

  int slot = blockIdx.z;
  const int* list = slot ? listB : listA;
  const int* cnt  = slot ? cntB  : cntA;
  int e = blockIdx.y;
  int pos = blockIdx.x * 64 + threadIdx.x;
  if (pos >= cnt[e]) return;
  int tid = threadIdx.x;
  int ent = list[e * BTOK + pos];
  int t = ent >> 1;

  float v0r[NQ], v0i[NQ], v1r[NQ], v1i[NQ];
  const float* qp0 = qp + (size_t)e * NL * NQ * 3;
  #pragma unroll
  for (int q = 0; q < NQ; ++q) {
    float a   = xin[(size_t)t * DDIM + q];
    float phi = qp0[q*3+0], th = qp0[q*3+1], om = qp0[q*3+2];
    float sa, ca;  sincosf(0.5f * a, &sa, &ca);
    float s,  c;   sincosf(0.5f * th, &s, &c);
    float sp, cp;  sincosf(0.5f * (phi + om), &sp, &cp);
    float sq_, cq_; sincosf(0.5f * (phi - om), &sq_, &cq_);
    v0r[q] =  c*cp*ca - s*cq_*sa;
    v0i[q] = -c*sp*ca - s*sq_*sa;
    v1r[q] =  s*cq_*ca + c*cp*sa;
    v1i[q] = -s*sq_*ca + c*sp*sa;
  }

  float Rr[16], Ri[16], Tr[16], Ti[16];
  Rr[0]=v0r[0]; Ri[0]=v0i[0]; Rr[1]=v1r[0]; Ri[1]=v1i[0];
  Tr[0]=v0r[4]; Ti[0]=v0i[4]; Tr[1]=v1r[4]; Ti[1]=v1i[4];
  #pragma unroll
  for (int q = 1; q < 4; ++q) {
    #pragma unroll
    for (int i = (1<<q)-1; i >= 0; --i) {
      float xr_ = Rr[i], xi_ = Ri[i];
      Rr[2*i+1] = xr_*v1r[q]   - xi_*v1i[q];
      Ri[2*i+1] = xr_*v1i[q]   + xi_*v1r[q];
      Rr[2*i]   = xr_*v0r[q]   - xi_*v0i[q];
      Ri[2*i]   = xr_*v0i[q]   + xi_*v0r[q];
      float yr_ = Tr[i], yi_ = Ti[i];
      Tr[2*i+1] = yr_*v1r[q+4] - yi_*v1i[q+4];
      Ti[2*i+1] = yr_*v1i[q+4] + yi_*v1r[q+4];
      Tr[2*i]   = yr_*v0r[q+4] - yi_*v0i[q+4];
      Ti[2*i]   = yr_*v0i[q+4] + yi_*v0r[q+4];
    }
  }
  #pragma unroll
  for (int i = 0; i < 16; ++i) { tTr[i*64+tid] = Tr[i]; tTi[i*64+tid] = Ti[i]; }

  #pragma unroll
  for (int hi = 0; hi < 16; ++hi) {
    float rr = Rr[hi], ri = Ri[hi];
    for (int lo = 0; lo < 16; ++lo) {
      float tr = tTr[lo*64+tid], ti = tTi[lo*64+tid];
      int j = pfx(hi*16 + lo);
      sre [j*64+tid] = rr*tr - ri*ti;
      simg[j*64+tid] = rr*ti + ri*tr;
    }
  }

  const float* qp1 = qp0 + NQ*3;
  for (int q = 0; q < NQ; ++q) {
    float phi = qp1[q*3+0], th = qp1[q*3+1], om = qp1[q*3+2];
    float s,  c;   sincosf(0.5f * th, &s, &c);
    float sp, cp;  sincosf(0.5f * (phi + om), &sp, &cp);
    float sq_, cq_; sincosf(0.5f * (phi - om), &sq_, &cq_);
    float M00r =  c*cp,  M00i = -c*sp;
    float M01r = -s*cq_, M01i = -s*sq_;
    float M10r =  s*cq_, M10i = -s*sq_;
    float M11r =  c*cp,  M11i =  c*sp;
    int bm = 1 << (7 - q);
    int lowm = bm - 1;
    #pragma unroll 8
    for (int pp = 0; pp < 128; ++pp) {
      int i0 = ((pp & ~lowm) << 1) | (pp & lowm);
      int i1 = i0 | bm;
      int o0 = i0*64+tid, o1 = i1*64+tid;
      float a0r = sre[o0], a0i = simg[o0];
      float a1r = sre[o1], a1i = simg[o1];
      sre [o0] = M00r*a0r - M00i*a0i + M01r*a1r - M01i*a1i;
      simg[o0] = M00r*a0i + M00i*a0r + M01r*a1i + M01i*a1r;
      sre [o1] = M10r*a0r - M10i*a0i + M11r*a1r - M11i*a1i;
      simg[o1] = M10r*a0i + M10i*a0r + M11r*a1i + M11i*a1r;
    }
  }

  float z[NQ] = {0.f,0.f,0.f,0.f,0.f,0.f,0.f,0.f};
  for (int i = 0; i < 256; ++i) {
    int o = i*64+tid;
    float rr = sre[o], ii = simg[o];
    float pb = rr*rr + ii*ii;
    int j = pfx(i);
    #pragma unroll
    for (int q = 0; q < NQ; ++q)
      z[q] += ((j >> (7 - q)) & 1) ? -pb : pb;
  }
  float* dst = q8 + (size_t)ent * 8;
  #pragma unroll
  for (int q = 0; q < NQ; ++q) dst[q] = z[q];
}

// ---------------------------------------------------------------------------
// w2 convert (+transpose): w2[e][k][n] fp32 -> whiT[e][n][k] bf16 (and
// wloT = bf16(w2 - hi) when LO) so the GEMM can stage B^T with
// global_load_lds + XOR-swizzled source.
// ---------------------------------------------------------------------------
template<bool LO>
__global__ __launch_bounds__(256) void k_wconv(
    const float* __restrict__ w2, unsigned short* __restrict__ whiT,
    unsigned short* __restrict__ wloT) {
  __shared__ float tile[64][68];
  int e = blockIdx.z, kt = blockIdx.x, nt = blockIdx.y;
  const float* src = w2 + ((size_t)e * 1024 + kt * 64) * 1024 + nt * 64;
  int tid = threadIdx.x;
  int jr = (tid & 15) * 4;
  int ir = tid >> 4;
  #pragma unroll
  for (int p = 0; p < 4; ++p) {
    float4 v = *(const float4*)&src[(size_t)(ir + p*16) * 1024 + jr];
    *(float4*)&tile[ir + p*16][jr] = v;
  }
  __syncthreads();
  int nl_ = tid >> 2;               // 0..63 (output row within tile)
  int kc = (tid & 3) * 16;          // k chunk
  short8 hi0, hi1, lo0, lo1;
  #pragma unroll
  for (int i = 0; i < 8; ++i) {
    float v = tile[kc + i][nl_];
    unsigned short h = f2bf(v);
    hi0[i] = (short)h;
    if (LO) lo0[i] = (short)f2bf(v - bf2f(h));
  }
  #pragma unroll
  for (int i = 0; i < 8; ++i) {
    float v = tile[kc + 8 + i][nl_];
    unsigned short h = f2bf(v);
    hi1[i] = (short)h;
    if (LO) lo1[i] = (short)f2bf(v - bf2f(h));
  }
  size_t orow = ((size_t)e * 1024 + nt * 64 + nl_) * 1024 + kt * 64 + kc;
  *(short8*)&whiT[orow]     = hi0;
  *(short8*)&whiT[orow + 8] = hi1;
  if (LO) {
    *(short8*)&wloT[orow]     = lo0;
    *(short8*)&wloT[orow + 8] = lo1;
  }
}

// ---------------------------------------------------------------------------
// MFMA expert MLP over one slot's entry lists.
//   h = relu(q8 @ rW + rb)  built in-kernel (fp32, split to bf16 hi/lo)
//   yacc[token] += selw * (h @ w2 + b2)   non-atomic (slot-unique rows)
// NSEG=3: h_hi*w_hi + h_hi*w_lo + h_lo*w_hi (fp32-class accuracy, block 0)
// NSEG=1: bf16 x bf16 (block 1; no downstream top-k)
// 128x128 tile, BK=64, 4 waves, 16x16x32 bf16 MFMA, XOR-swizzled LDS.
// grid: x = e*8+ct, y = rt -> linear%8 = ct -> XCD-resident B panels.
// ---------------------------------------------------------------------------
template<int NSEG>
__global__ __launch_bounds__(256, 2) void k_gemm(
    const float* __restrict__ q8, const float* __restrict__ rW,
    const float* __restrict__ rb, const unsigned short* __restrict__ whiT,
    const unsigned short* __restrict__ wloT, const float* __restrict__ b2,
    const int* __restrict__ list, const int* __restrict__ cnt,
    const float* __restrict__ selw, float* __restrict__ yacc) {
  constexpr int NA = (NSEG == 3) ? 2 : 1;
  int bx = blockIdx.x;
  int e = bx >> 3, ct = bx & 7, rt = blockIdx.y;
  int n = cnt[e];
  int r0 = rt * 128;
  if (r0 >= n) return;

  __shared__ unsigned short sA[NA][128 * 64];
  __shared__ unsigned short sB[NA][128 * 64];
  __shared__ float srWt[2][64][8];
  __shared__ float srb[2][64];
  __shared__ int   sent[128];
  __shared__ float sw_[128];
  __shared__ float sb2[128];

  int tid = threadIdx.x;
  int wave = tid >> 6, lane = tid & 63;
  int rbase = (tid & 31) * 4;       // h-build rows
  int kseg = tid >> 5;              // h-build k chunk (8 wide)

  const float* rWe = rW + (size_t)e * 8 * 1024;

  // q rows for h-build (registers, zero for padding rows)
  float q[4][8];
  #pragma unroll
  for (int rr = 0; rr < 4; ++rr) {
    int r = r0 + rbase + rr;
    if (r < n) {
      int ent = list[e * BTOK + r];
      const float* qp_ = q8 + (size_t)ent * 8;
      float4 a = *(const float4*)qp_;
      float4 b = *(const float4*)(qp_ + 4);
      q[rr][0]=a.x; q[rr][1]=a.y; q[rr][2]=a.z; q[rr][3]=a.w;
      q[rr][4]=b.x; q[rr][5]=b.y; q[rr][6]=b.z; q[rr][7]=b.w;
    } else {
      #pragma unroll
      for (int j = 0; j < 8; ++j) q[rr][j] = 0.f;
    }
  }
  if (tid < 128) {
    int r = r0 + tid;
    int ent = (r < n) ? list[e * BTOK + r] : -1;
    sent[tid] = ent;
    sw_[tid] = (ent >= 0) ? selw[ent] : 0.f;
    sb2[tid] = b2[(size_t)e * 1024 + ct * 128 + tid];
  }
  // prologue srWt[0]/srb[0]
  {
    int j = tid & 7, kk = tid >> 3;
    srWt[0][kk][j]      = rWe[j * 1024 + kk];
    srWt[0][kk + 32][j] = rWe[j * 1024 + kk + 32];
  }
  if (tid < 64) srb[0][tid] = rb[(size_t)e * 1024 + tid];

  f32x4 acc[4][4];
  #pragma unroll
  for (int m = 0; m < 4; ++m)
    #pragma unroll
    for (int nn = 0; nn < 4; ++nn)
      acc[m][nn] = (f32x4){0.f, 0.f, 0.f, 0.f};

  const unsigned short* Bh0 = whiT + ((size_t)(e * 1024 + ct * 128)) * 1024;
  const unsigned short* Bl0 = (NSEG == 3)
      ? wloT + ((size_t)(e * 1024 + ct * 128)) * 1024 : Bh0;

  int wm = wave >> 1, wn = wave & 1;
  int fr = lane & 15, fk = lane >> 4;

  for (int ks = 0; ks < 16; ++ks) {
    int buf = ks & 1;
    __syncthreads();                              // B1
    // issue B tile loads (pre-swizzled global source, linear LDS dest)
    #pragma unroll
    for (int s = 0; s < NA; ++s) {
      const unsigned short* bsrc = (s ? Bl0 : Bh0) + ks * 64;
      #pragma unroll
      for (int i = 0; i < 4; ++i) {
        int slotbase = (wave * 4 + i) * 64;
        int slot = slotbase + lane;
        int nrow = slot >> 3, c = slot & 7;
        const unsigned short* g = bsrc + (size_t)nrow * 1024 + ((c ^ (nrow & 7)) << 3);
        gload_lds16(g, &sB[s][slotbase * 8]);
      }
    }
    // stage next srWt/srb
    if (ks + 1 < 16) {
      int j = tid & 7, kk = tid >> 3;
      srWt[buf ^ 1][kk][j]      = rWe[j * 1024 + (ks + 1) * 64 + kk];
      srWt[buf ^ 1][kk + 32][j] = rWe[j * 1024 + (ks + 1) * 64 + kk + 32];
      if (tid < 64) srb[buf ^ 1][tid] = rb[(size_t)e * 1024 + (ks + 1) * 64 + tid];
    }
    // h-build (fp32) -> bf16 hi/lo, swizzled ds_write
    {
      short8 vh[4], vl[4];
      #pragma unroll
      for (int kk8 = 0; kk8 < 8; ++kk8) {
        int kk = kseg * 8 + kk8;
        float4 w0 = *(const float4*)&srWt[buf][kk][0];
        float4 w1 = *(const float4*)&srWt[buf][kk][4];
        float rbv = srb[buf][kk];
        #pragma unroll
        for (int rr = 0; rr < 4; ++rr) {
          float v = rbv + q[rr][0]*w0.x + q[rr][1]*w0.y + q[rr][2]*w0.z + q[rr][3]*w0.w
                        + q[rr][4]*w1.x + q[rr][5]*w1.y + q[rr][6]*w1.z + q[rr][7]*w1.w;
          v = fmaxf(v, 0.f);
          unsigned short h = f2bf(v);
          vh[rr][kk8] = (short)h;
          if (NSEG == 3) vl[rr][kk8] = (short)f2bf(v - bf2f(h));
        }
      }
      #pragma unroll
      for (int rr = 0; rr < 4; ++rr) {
        int r = rbase + rr;
        int sl = kseg ^ (r & 7);
        *(short8*)&sA[0][r * 64 + sl * 8] = vh[rr];
        if (NSEG == 3) *(short8*)&sA[1][r * 64 + sl * 8] = vl[rr];
      }
    }
    __syncthreads();                              // B2 (drains vmcnt+lgkm)
    // MFMA phase
    short8 ah[4][2], bh[4][2];
    #pragma unroll
    for (int m = 0; m < 4; ++m)
      #pragma unroll
      for (int kh = 0; kh < 2; ++kh) {
        int r = wm * 64 + m * 16 + fr;
        int ch = kh * 4 + fk;
        ah[m][kh] = *(const short8*)&sA[0][r * 64 + (ch ^ (r & 7)) * 8];
      }
    #pragma unroll
    for (int nn = 0; nn < 4; ++nn)
      #pragma unroll
      for (int kh = 0; kh < 2; ++kh) {
        int nr = wn * 64 + nn * 16 + fr;
        int ch = kh * 4 + fk;
        bh[nn][kh] = *(const short8*)&sB[0][nr * 64 + (ch ^ (nr & 7)) * 8];
      }
    #pragma unroll
    for (int m = 0; m < 4; ++m)
      #pragma unroll
      for (int nn = 0; nn < 4; ++nn)
        #pragma unroll
        for (int kh = 0; kh < 2; ++kh)
          acc[m][nn] = __builtin_amdgcn_mfma_f32_16x16x32_bf16(
              ah[m][kh], bh[nn][kh], acc[m][nn], 0, 0, 0);
    if (NSEG == 3) {
      short8 bl[4][2];
      #pragma unroll
      for (int nn = 0; nn < 4; ++nn)
        #pragma unroll
        for (int kh = 0; kh < 2; ++kh) {
          int nr = wn * 64 + nn * 16 + fr;
          int ch = kh * 4 + fk;
          bl[nn][kh] = *(const short8*)&sB[1][nr * 64 + (ch ^ (nr & 7)) * 8];
        }
      #pragma unroll
      for (int m = 0; m < 4; ++m)
        #pragma unroll
        for (int nn = 0; nn < 4; ++nn)
          #pragma unroll
          for (int kh = 0; kh < 2; ++kh)
            acc[m][nn] = __builtin_amdgcn_mfma_f32_16x16x32_bf16(
                ah[m][kh], bl[nn][kh], acc[m][nn], 0, 0, 0);
      short8 al[4][2];
      #pragma unroll
      for (int m = 0; m < 4; ++m)
        #pragma unroll
        for (int kh = 0; kh < 2; ++kh) {
          int r = wm * 64 + m * 16 + fr;
          int ch = kh * 4 + fk;
          al[m][kh] = *(const short8*)&sA[1][r * 64 + (ch ^ (r & 7)) * 8];
        }
      #pragma unroll
      for (int m = 0; m < 4; ++m)
        #pragma unroll
        for (int nn = 0; nn < 4; ++nn)
          #pragma unroll
          for (int kh = 0; kh < 2; ++kh)
            acc[m][nn] = __builtin_amdgcn_mfma_f32_16x16x32_bf16(
                al[m][kh], bh[nn][kh], acc[m][nn], 0, 0, 0);
    }
  }

  // epilogue: yacc[token] += w * (acc + b2)  (non-atomic, slot-unique rows)
  #pragma unroll
  for (int m = 0; m < 4; ++m) {
    #pragma unroll
    for (int nn = 0; nn < 4; ++nn) {
      f32x4 a = acc[m][nn];
      int colL = wn * 64 + nn * 16 + fr;
      int col = ct * 128 + colL;
      float b2v = sb2[colL];
      #pragma unroll
      for (int g = 0; g < 4; ++g) {
        int r = wm * 64 + m * 16 + fk * 4 + g;
        int ent = sent[r];
        if (ent >= 0) {
          float* p = yacc + ((size_t)(ent >> 1)) * 1024 + col;
          *p += sw_[r] * (a[g] + b2v);
        }
      }
    }
  }
}

// ---------------------------------------------------------------------------
// LayerNorm (two-pass), in-place capable (yacc == out).
// ---------------------------------------------------------------------------
__global__ __launch_bounds__(256) void k_ln(
    const float* __restrict__ yacc, const float* __restrict__ g,
    const float* __restrict__ bta, float* __restrict__ out) {
  int t = blockIdx.x, tid = threadIdx.x;
  const float4* yr = (const float4*)(yacc + (size_t)t * DDIM);
  float4 y = yr[tid];
  float s = y.x + y.y + y.z + y.w;
  #pragma unroll
  for (int off = 32; off; off >>= 1) s += __shfl_xor(s, off);
  __shared__ float red1[4], red2[4];
  int wave = tid >> 6, lane = tid & 63;
  if (lane == 0) red1[wave] = s;
  __syncthreads();
  float mu = (red1[0]+red1[1]+red1[2]+red1[3]) * (1.f/(float)DDIM);
  float ax = y.x - mu, ay = y.y - mu, az = y.z - mu, aw = y.w - mu;
  float sq = ax*ax + ay*ay + az*az + aw*aw;
  #pragma unroll
  for (int off = 32; off; off >>= 1) sq += __shfl_xor(sq, off);
  if (lane == 0) red2[wave] = sq;
  __syncthreads();
  float var = (red2[0]+red2[1]+red2[2]+red2[3]) * (1.f/(float)DDIM);
  float rs = 1.f / sqrtf(var + 1e-5f);
  float4 gv = ((const float4*)g)[tid];
  float4 bv = ((const float4*)bta)[tid];
  float4 o;
  o.x = ax*rs*gv.x + bv.x;
  o.y = ay*rs*gv.y + bv.y;
  o.z = az*rs*gv.z + bv.z;
  o.w = aw*rs*gv.w + bv.w;
  ((float4*)(out + (size_t)t * DDIM))[tid] = o;
}

// ---------------------------------------------------------------------------
extern "C" void kernel_launch(void* const* d_in, const int* in_sizes, int n_in,
                              void* d_out, int out_size, void* d_ws, size_t ws_size,
                              hipStream_t stream) {
  const float* x   = (const float*)d_in[0];
  const float* gW  = (const float*)d_in[1];
  const float* gb  = (const float*)d_in[2];
  const float* qp  = (const float*)d_in[3];
  const float* rW  = (const float*)d_in[4];
  const float* rb  = (const float*)d_in[5];
  const float* w2  = (const float*)d_in[6];
  const float* b2  = (const float*)d_in[7];
  const float* lg  = (const float*)d_in[8];
  const float* lb  = (const float*)d_in[9];
  float* out = (float*)d_out;     // doubles as yacc (residual accumulator)

  char* ws = (char*)d_ws;
  unsigned short* whiT = (unsigned short*)ws;                       // 16MB
  unsigned short* wloT = (unsigned short*)(ws + 16777216);          // 16MB
  float* q8   = (float*)(ws + 33554432);                            // 512KB
  float* selw = (float*)(ws + 34078720);                            // 64KB
  int* listA  = (int*)(ws + 34144256);                              // 256KB
  int* listB  = (int*)(ws + 34406400);                              // 256KB
  int* cntA   = (int*)(ws + 34668544);                              // 32B
  int* cntB   = (int*)(ws + 34668576);                              // 32B

  hipFuncSetAttribute(reinterpret_cast<const void*>(k_qsim),
      hipFuncAttributeMaxDynamicSharedMemorySize, 139264);

  // block-0 w2 -> bf16 hi/lo transposed
  k_wconv<true><<<dim3(16, 16, 8), 256, 0, stream>>>(w2, whiT, wloT);

  for (int blk = 0; blk < NB; ++blk) {
    const float* xin = blk ? (const float*)out : x;
    hipMemsetAsync(cntA, 0, 64, stream);   // cntA+cntB adjacent
    k_gate<<<dim3(BTOK/4), 256, 0, stream>>>(
        xin, gW + (size_t)blk * DDIM * NEXP, gb + (size_t)blk * NEXP,
        selw, cntA, cntB, listA, listB, out);
    k_qsim<<<dim3(BTOK/64, NEXP, 2), 64, 139264, stream>>>(
        xin, qp + (size_t)blk * NEXP * NL * NQ * 3, listA, listB, cntA, cntB, q8);
    const float* rWb = rW + (size_t)blk * NEXP * NQ * HDIM;
    const float* rbb = rb + (size_t)blk * NEXP * HDIM;
    const float* b2b = b2 + (size_t)blk * NEXP * DDIM;
    if (blk == 0) {
      k_gemm<3><<<dim3(64, 64), 256, 0, stream>>>(
          q8, rWb, rbb, whiT, wloT, b2b, listA, cntA, selw, out);
      k_gemm<3><<<dim3(64, 64), 256, 0, stream>>>(
          q8, rWb, rbb, whiT, wloT, b2b, listB, cntB, selw, out);
      // block-1 w2 -> bf16 (hi only), overwrites whiT after blk0 GEMMs
      k_wconv<false><<<dim3(16, 16, 8), 256, 0, stream>>>(
          w2 + (size_t)NEXP * HDIM * DDIM, whiT, wloT);
    } else {
      k_gemm<1><<<dim3(64, 64), 256, 0, stream>>>(
          q8, rWb, rbb, whiT, wloT, b2b, listA, cntA, selw, out);
      k_gemm<1><<<dim3(64, 64), 256, 0, stream>>>(
          q8, rWb, rbb, whiT, wloT, b2b, listB, cntB, selw, out);
    }
    k_ln<<<dim3(BTOK), 256, 0, stream>>>(
        out, lg + (size_t)blk * DDIM, lb + (size_t)blk * DDIM, out);
  }
}

// Round 4
// 1195.637 us; speedup vs baseline: 2.2911x; 1.3769x over previous
//
#include <hip/hip_runtime.h>
#include <hip/hip_bf16.h>

#define NB    2
#define BTOK  8192
#define DDIM  1024
#define HDIM  1024
#define NEXP  8
#define NQ    8
#define NL    2

typedef __attribute__((ext_vector_type(8))) short short8;
typedef __attribute__((ext_vector_type(4))) float f32x4;

__device__ __forceinline__ unsigned short f2bf(float v) {
  union { __hip_bfloat16 b; unsigned short u; } cv;
  cv.b = __float2bfloat16(v);
  return cv.u;
}
__device__ __forceinline__ float bf2f(unsigned short u) {
  union { unsigned short u; __hip_bfloat16 b; } cv;
  cv.u = u;
  return __bfloat162float(cv.b);
}

__device__ __forceinline__ void gload_lds16(const void* g, void* l) {
  __builtin_amdgcn_global_load_lds(
      (const __attribute__((address_space(1))) unsigned int*)g,
      (__attribute__((address_space(3))) unsigned int*)l, 16, 0, 0);
}

// ---------------------------------------------------------------------------
// Gate: logits = x@gW + gb, softmax, top-2 (strict > = lowest-index ties),
// weights = softmax over the two top PROBS. Seeds yacc(=d_out) with x.
// ---------------------------------------------------------------------------
__global__ __launch_bounds__(256) void k_gate(
    const float* __restrict__ xin, const float* __restrict__ gW,
    const float* __restrict__ gb, float* __restrict__ selw,
    int* __restrict__ cntA, int* __restrict__ cntB,
    int* __restrict__ listA, int* __restrict__ listB,
    float* __restrict__ yacc) {
  __shared__ float sgw[NEXP][DDIM];   // transposed gate weights, 32KB
  int tid = threadIdx.x;
  for (int i = tid; i < DDIM * NEXP; i += 256)
    sgw[i & 7][i >> 3] = gW[i];
  __syncthreads();

  int wave = tid >> 6, lane = tid & 63;
  int t = blockIdx.x * 4 + wave;
  const float4* xr = (const float4*)(xin + (size_t)t * DDIM);
  float4* yw = (float4*)(yacc + (size_t)t * DDIM);

  float acc[NEXP] = {0.f,0.f,0.f,0.f,0.f,0.f,0.f,0.f};
  #pragma unroll
  for (int c = 0; c < 4; ++c) {
    int f4 = c * 64 + lane;
    float4 xv = xr[f4];
    yw[f4] = xv;                      // yacc = x
    int d0 = f4 * 4;
    #pragma unroll
    for (int e = 0; e < NEXP; ++e) {
      float4 gv = *(const float4*)&sgw[e][d0];
      acc[e] += xv.x*gv.x + xv.y*gv.y + xv.z*gv.z + xv.w*gv.w;
    }
  }
  #pragma unroll
  for (int e = 0; e < NEXP; ++e) {
    float v = acc[e];
    #pragma unroll
    for (int off = 32; off; off >>= 1) v += __shfl_xor(v, off);
    acc[e] = v;
  }

  if (lane == 0) {
    float p[NEXP];
    float m = -3.4e38f;
    #pragma unroll
    for (int e = 0; e < NEXP; ++e) { p[e] = acc[e] + gb[e]; m = fmaxf(m, p[e]); }
    float s = 0.f;
    #pragma unroll
    for (int e = 0; e < NEXP; ++e) { p[e] = expf(p[e] - m); s += p[e]; }
    float inv = 1.f / s;
    #pragma unroll
    for (int e = 0; e < NEXP; ++e) p[e] *= inv;
    int i1 = 0;
    #pragma unroll
    for (int e = 1; e < NEXP; ++e) if (p[e] > p[i1]) i1 = e;
    int i2 = (i1 == 0) ? 1 : 0;
    #pragma unroll
    for (int e = 0; e < NEXP; ++e)
      if (e != i1 && e != i2 && p[e] > p[i2]) i2 = e;
    float pa = p[i1], pb = p[i2];
    float eb = expf(pb - pa);
    float wa = 1.f / (1.f + eb);
    float wb = eb * wa;
    int t2 = t * 2;
    selw[t2]   = wa;
    selw[t2+1] = wb;
    int pos1 = atomicAdd(&cntA[i1], 1);
    listA[i1 * BTOK + pos1] = t2;
    int pos2 = atomicAdd(&cntB[i2], 1);
    listB[i2 * BTOK + pos2] = t2 + 1;
  }
}

// ---------------------------------------------------------------------------
// Register-resident quantum sim: 4 lanes per (token,expert), 64 complex amps
// per lane, zero LDS, zero barriers.
// Basis index j = sub*64 + local (qubit q <-> bit 7-q of j); state is stored
// post-CNOT-chain-1, so the product build uses i = j ^ (j>>1):
//   qubit0 sel = sub1; qubit1 sel = sub0^sub1; qubit2 sel = l5^sub0 (cndmask)
//   qubits 3..7 sel = compile-time parity of local -> unrolled doubling.
// Layer-2: qubits 2..7 = in-register pair updates; qubits 1,0 = shfl_xor 1,2.
// CNOT-chain-2 folds into readout signs: parity(local bits) ^ (sub0^sub1).
// ---------------------------------------------------------------------------
__global__ __launch_bounds__(256, 1) void k_qsim(
    const float* __restrict__ xin, const float* __restrict__ qp,
    const int* __restrict__ listA, const int* __restrict__ listB,
    const int* __restrict__ cntA, const int* __restrict__ cntB,
    float* __restrict__ q8) {
  int slot = blockIdx.z;
  const int* list = slot ? listB : listA;
  const int* cnt  = slot ? cntB  : cntA;
  int e = blockIdx.y;
  int tid = threadIdx.x;
  int grp = tid >> 2, sub = tid & 3;
  int pos = blockIdx.x * 64 + grp;
  if (pos >= cnt[e]) return;
  int ent = list[e * BTOK + pos];
  int t = ent >> 1;
  int sub0 = sub & 1, sub1 = sub >> 1;

  // layer-0 rotated per-qubit 2-vectors v = Rot @ [cos(a/2), sin(a/2)]
  float v0r[8], v0i[8], v1r[8], v1i[8];
  {
    const float* qp0 = qp + (size_t)e * (NL * NQ * 3);
    float4 a0 = *(const float4*)(xin + (size_t)t * DDIM);
    float4 a1 = *(const float4*)(xin + (size_t)t * DDIM + 4);
    float aa[8] = {a0.x,a0.y,a0.z,a0.w,a1.x,a1.y,a1.z,a1.w};
    #pragma unroll
    for (int q = 0; q < 8; ++q) {
      float a   = aa[q];
      float phi = qp0[q*3+0], th = qp0[q*3+1], om = qp0[q*3+2];
      float sa, ca;  sincosf(0.5f * a, &sa, &ca);
      float s,  c;   sincosf(0.5f * th, &s, &c);
      float sp, cp;  sincosf(0.5f * (phi + om), &sp, &cp);
      float sq_, cq_; sincosf(0.5f * (phi - om), &sq_, &cq_);
      v0r[q] =  c*cp*ca - s*cq_*sa;
      v0i[q] = -c*sp*ca - s*sq_*sa;
      v1r[q] =  s*cq_*ca + c*cp*sa;
      v1i[q] = -s*sq_*ca + c*sp*sa;
    }
  }

  // product build into 64 register amps (fully compile-time indexed)
  float ar[64], ai[64];
  {
    int s01 = sub0 ^ sub1;
    float f0r = sub1 ? v1r[0] : v0r[0], f0i = sub1 ? v1i[0] : v0i[0];
    float f1r = s01  ? v1r[1] : v0r[1], f1i = s01  ? v1i[1] : v0i[1];
    float Pr = f0r*f1r - f0i*f1i, Pi = f0r*f1i + f0i*f1r;
    float b0r = sub0 ? v1r[2] : v0r[2], b0i = sub0 ? v1i[2] : v0i[2];
    float b1r = sub0 ? v0r[2] : v1r[2], b1i = sub0 ? v0i[2] : v1i[2];
    ar[0]  = Pr*b0r - Pi*b0i;  ai[0]  = Pr*b0i + Pi*b0r;   // l5 = 0
    ar[32] = Pr*b1r - Pi*b1i;  ai[32] = Pr*b1i + Pi*b1r;   // l5 = 1
    #pragma unroll
    for (int lev = 0; lev < 5; ++lev) {       // qubit 3+lev, bit k = 4-lev
      const int k = 4 - lev;
      const int np = 2 << lev;
      #pragma unroll
      for (int m = np - 1; m >= 0; --m) {
        const int p = m << (k + 1);
        const int prevb = m & 1;              // bit k+1 of p
        const int q = 3 + lev;
        float pr = ar[p], pj = ai[p];
        // child bit b selector = b ^ prevb (all compile-time picks)
        float s0r = prevb ? v1r[q] : v0r[q], s0i = prevb ? v1i[q] : v0i[q];
        float s1r = prevb ? v0r[q] : v1r[q], s1i = prevb ? v0i[q] : v1i[q];
        ar[p | (1 << k)] = pr*s1r - pj*s1i;
        ai[p | (1 << k)] = pr*s1i + pj*s1r;
        ar[p]            = pr*s0r - pj*s0i;
        ai[p]            = pr*s0i + pj*s0r;
      }
    }
  }

  // layer-1 Rot gates
  const float* qp1 = qp + (size_t)e * (NL * NQ * 3) + NQ * 3;
  // qubits 2..7: thread-local pairs
  #pragma unroll
  for (int qq = 2; qq < 8; ++qq) {
    float phi = qp1[qq*3+0], th = qp1[qq*3+1], om = qp1[qq*3+2];
    float s,  c;   sincosf(0.5f * th, &s, &c);
    float sp, cp;  sincosf(0.5f * (phi + om), &sp, &cp);
    float sq_, cq_; sincosf(0.5f * (phi - om), &sq_, &cq_);
    float M00r =  c*cp,  M00i = -c*sp;
    float M01r = -s*cq_, M01i = -s*sq_;
    float M10r =  s*cq_, M10i = -s*sq_;
    float M11r =  c*cp,  M11i =  c*sp;
    const int bm = 1 << (7 - qq);
    #pragma unroll
    for (int pp = 0; pp < 32; ++pp) {
      const int i0 = ((pp & ~(bm - 1)) << 1) | (pp & (bm - 1));
      const int i1 = i0 | bm;
      float a0r = ar[i0], a0i = ai[i0], a1r = ar[i1], a1i = ai[i1];
      ar[i0] = M00r*a0r - M00i*a0i + M01r*a1r - M01i*a1i;
      ai[i0] = M00r*a0i + M00i*a0r + M01r*a1i + M01i*a1r;
      ar[i1] = M10r*a0r - M10i*a0i + M11r*a1r - M11i*a1i;
      ai[i1] = M10r*a0i + M10i*a0r + M11r*a1i + M11i*a1r;
    }
  }
  // qubit 1 (lane mask 1, high = sub0) then qubit 0 (mask 2, high = sub1)
  #pragma unroll
  for (int g = 0; g < 2; ++g) {
    const int qq = 1 - g;
    const int mask = g ? 2 : 1;
    int high = g ? sub1 : sub0;
    float phi = qp1[qq*3+0], th = qp1[qq*3+1], om = qp1[qq*3+2];
    float s,  c;   sincosf(0.5f * th, &s, &c);
    float sp, cp;  sincosf(0.5f * (phi + om), &sp, &cp);
    float sq_, cq_; sincosf(0.5f * (phi - om), &sq_, &cq_);
    float M00r =  c*cp,  M00i = -c*sp;
    float M01r = -s*cq_, M01i = -s*sq_;
    float M10r =  s*cq_, M10i = -s*sq_;
    float M11r =  c*cp,  M11i =  c*sp;
    float CL0r = high ? M10r : M00r, CL0i = high ? M10i : M00i;
    float CL1r = high ? M11r : M01r, CL1i = high ? M11i : M01i;
    #pragma unroll
    for (int l = 0; l < 64; ++l) {
      float pr = ar[l], pj = ai[l];
      float or_ = __shfl_xor(pr, mask);
      float oi_ = __shfl_xor(pj, mask);
      float a0r = high ? or_ : pr, a0i = high ? oi_ : pj;
      float a1r = high ? pr : or_, a1i = high ? pj : oi_;
      ar[l] = CL0r*a0r - CL0i*a0i + CL1r*a1r - CL1i*a1i;
      ai[l] = CL0r*a0i + CL0i*a0r + CL1r*a1i + CL1i*a1r;
    }
  }

  // readout with CNOT-chain-2 folded into signs
  float S = 0.f, zt0=0.f, zt1=0.f, zt2=0.f, zt3=0.f, zt4=0.f, zt5=0.f;
  #pragma unroll
  for (int l = 0; l < 64; ++l) {
    float pb = ar[l]*ar[l] + ai[l]*ai[l];
    S += pb;
    zt0 += (__builtin_popcount(l >> 5) & 1) ? -pb : pb;
    zt1 += (__builtin_popcount(l >> 4) & 1) ? -pb : pb;
    zt2 += (__builtin_popcount(l >> 3) & 1) ? -pb : pb;
    zt3 += (__builtin_popcount(l >> 2) & 1) ? -pb : pb;
    zt4 += (__builtin_popcount(l >> 1) & 1) ? -pb : pb;
    zt5 += (__builtin_popcount(l) & 1) ? -pb : pb;
  }
  int cc = sub0 ^ sub1;
  float sgnc = cc ? -1.f : 1.f;
  float z0 = sub1 ? -S : S;
  float z1 = cc ? -S : S;
  float z2 = sgnc*zt0, z3 = sgnc*zt1, z4 = sgnc*zt2;
  float z5 = sgnc*zt3, z6 = sgnc*zt4, z7 = sgnc*zt5;
  z0 += __shfl_xor(z0,1); z0 += __shfl_xor(z0,2);
  z1 += __shfl_xor(z1,1); z1 += __shfl_xor(z1,2);
  z2 += __shfl_xor(z2,1); z2 += __shfl_xor(z2,2);
  z3 += __shfl_xor(z3,1); z3 += __shfl_xor(z3,2);
  z4 += __shfl_xor(z4,1); z4 += __shfl_xor(z4,2);
  z5 += __shfl_xor(z5,1); z5 += __shfl_xor(z5,2);
  z6 += __shfl_xor(z6,1); z6 += __shfl_xor(z6,2);
  z7 += __shfl_xor(z7,1); z7 += __shfl_xor(z7,2);
  float w0 = z0, w1 = z1;
  if (sub == 1)      { w0 = z2; w1 = z3; }
  else if (sub == 2) { w0 = z4; w1 = z5; }
  else if (sub == 3) { w0 = z6; w1 = z7; }
  *(float2*)(q8 + (size_t)ent * 8 + sub * 2) = make_float2(w0, w1);
}

// ---------------------------------------------------------------------------
// w2 convert (+transpose): w2[e][k][n] fp32 -> whiT[e][n][k] bf16 (and
// wloT = bf16(w2 - hi) when LO).
// ---------------------------------------------------------------------------
template<bool LO>
__global__ __launch_bounds__(256) void k_wconv(
    const float* __restrict__ w2, unsigned short* __restrict__ whiT,
    unsigned short* __restrict__ wloT) {
  __shared__ float tile[64][68];
  int e = blockIdx.z, kt = blockIdx.x, nt = blockIdx.y;
  const float* src = w2 + ((size_t)e * 1024 + kt * 64) * 1024 + nt * 64;
  int tid = threadIdx.x;
  int jr = (tid & 15) * 4;
  int ir = tid >> 4;
  #pragma unroll
  for (int p = 0; p < 4; ++p) {
    float4 v = *(const float4*)&src[(size_t)(ir + p*16) * 1024 + jr];
    *(float4*)&tile[ir + p*16][jr] = v;
  }
  __syncthreads();
  int nl_ = tid >> 2;
  int kc = (tid & 3) * 16;
  short8 hi0, hi1, lo0, lo1;
  #pragma unroll
  for (int i = 0; i < 8; ++i) {
    float v = tile[kc + i][nl_];
    unsigned short h = f2bf(v);
    hi0[i] = (short)h;
    if (LO) lo0[i] = (short)f2bf(v - bf2f(h));
  }
  #pragma unroll
  for (int i = 0; i < 8; ++i) {
    float v = tile[kc + 8 + i][nl_];
    unsigned short h = f2bf(v);
    hi1[i] = (short)h;
    if (LO) lo1[i] = (short)f2bf(v - bf2f(h));
  }
  size_t orow = ((size_t)e * 1024 + nt * 64 + nl_) * 1024 + kt * 64 + kc;
  *(short8*)&whiT[orow]     = hi0;
  *(short8*)&whiT[orow + 8] = hi1;
  if (LO) {
    *(short8*)&wloT[orow]     = lo0;
    *(short8*)&wloT[orow + 8] = lo1;
  }
}

// ---------------------------------------------------------------------------
// MFMA expert MLP over one slot's entry lists (unchanged from round 2).
// ---------------------------------------------------------------------------
template<int NSEG>
__global__ __launch_bounds__(256, 2) void k_gemm(
    const float* __restrict__ q8, const float* __restrict__ rW,
    const float* __restrict__ rb, const unsigned short* __restrict__ whiT,
    const unsigned short* __restrict__ wloT, const float* __restrict__ b2,
    const int* __restrict__ list, const int* __restrict__ cnt,
    const float* __restrict__ selw, float* __restrict__ yacc) {
  constexpr int NA = (NSEG == 3) ? 2 : 1;
  int bx = blockIdx.x;
  int e = bx >> 3, ct = bx & 7, rt = blockIdx.y;
  int n = cnt[e];
  int r0 = rt * 128;
  if (r0 >= n) return;

  __shared__ unsigned short sA[NA][128 * 64];
  __shared__ unsigned short sB[NA][128 * 64];
  __shared__ float srWt[2][64][8];
  __shared__ float srb[2][64];
  __shared__ int   sent[128];
  __shared__ float sw_[128];
  __shared__ float sb2[128];

  int tid = threadIdx.x;
  int wave = tid >> 6, lane = tid & 63;
  int rbase = (tid & 31) * 4;
  int kseg = tid >> 5;

  const float* rWe = rW + (size_t)e * 8 * 1024;

  float q[4][8];
  #pragma unroll
  for (int rr = 0; rr < 4; ++rr) {
    int r = r0 + rbase + rr;
    if (r < n) {
      int ent = list[e * BTOK + r];
      const float* qp_ = q8 + (size_t)ent * 8;
      float4 a = *(const float4*)qp_;
      float4 b = *(const float4*)(qp_ + 4);
      q[rr][0]=a.x; q[rr][1]=a.y; q[rr][2]=a.z; q[rr][3]=a.w;
      q[rr][4]=b.x; q[rr][5]=b.y; q[rr][6]=b.z; q[rr][7]=b.w;
    } else {
      #pragma unroll
      for (int j = 0; j < 8; ++j) q[rr][j] = 0.f;
    }
  }
  if (tid < 128) {
    int r = r0 + tid;
    int ent = (r < n) ? list[e * BTOK + r] : -1;
    sent[tid] = ent;
    sw_[tid] = (ent >= 0) ? selw[ent] : 0.f;
    sb2[tid] = b2[(size_t)e * 1024 + ct * 128 + tid];
  }
  {
    int j = tid & 7, kk = tid >> 3;
    srWt[0][kk][j]      = rWe[j * 1024 + kk];
    srWt[0][kk + 32][j] = rWe[j * 1024 + kk + 32];
  }
  if (tid < 64) srb[0][tid] = rb[(size_t)e * 1024 + tid];

  f32x4 acc[4][4];
  #pragma unroll
  for (int m = 0; m < 4; ++m)
    #pragma unroll
    for (int nn = 0; nn < 4; ++nn)
      acc[m][nn] = (f32x4){0.f, 0.f, 0.f, 0.f};

  const unsigned short* Bh0 = whiT + ((size_t)(e * 1024 + ct * 128)) * 1024;
  const unsigned short* Bl0 = (NSEG == 3)
      ? wloT + ((size_t)(e * 1024 + ct * 128)) * 1024 : Bh0;

  int wm = wave >> 1, wn = wave & 1;
  int fr = lane & 15, fk = lane >> 4;

  for (int ks = 0; ks < 16; ++ks) {
    int buf = ks & 1;
    __syncthreads();
    #pragma unroll
    for (int s = 0; s < NA; ++s) {
      const unsigned short* bsrc = (s ? Bl0 : Bh0) + ks * 64;
      #pragma unroll
      for (int i = 0; i < 4; ++i) {
        int slotbase = (wave * 4 + i) * 64;
        int slot = slotbase + lane;
        int nrow = slot >> 3, c = slot & 7;
        const unsigned short* g = bsrc + (size_t)nrow * 1024 + ((c ^ (nrow & 7)) << 3);
        gload_lds16(g, &sB[s][slotbase * 8]);
      }
    }
    if (ks + 1 < 16) {
      int j = tid & 7, kk = tid >> 3;
      srWt[buf ^ 1][kk][j]      = rWe[j * 1024 + (ks + 1) * 64 + kk];
      srWt[buf ^ 1][kk + 32][j] = rWe[j * 1024 + (ks + 1) * 64 + kk + 32];
      if (tid < 64) srb[buf ^ 1][tid] = rb[(size_t)e * 1024 + (ks + 1) * 64 + tid];
    }
    {
      short8 vh[4], vl[4];
      #pragma unroll
      for (int kk8 = 0; kk8 < 8; ++kk8) {
        int kk = kseg * 8 + kk8;
        float4 w0 = *(const float4*)&srWt[buf][kk][0];
        float4 w1 = *(const float4*)&srWt[buf][kk][4];
        float rbv = srb[buf][kk];
        #pragma unroll
        for (int rr = 0; rr < 4; ++rr) {
          float v = rbv + q[rr][0]*w0.x + q[rr][1]*w0.y + q[rr][2]*w0.z + q[rr][3]*w0.w
                        + q[rr][4]*w1.x + q[rr][5]*w1.y + q[rr][6]*w1.z + q[rr][7]*w1.w;
          v = fmaxf(v, 0.f);
          unsigned short h = f2bf(v);
          vh[rr][kk8] = (short)h;
          if (NSEG == 3) vl[rr][kk8] = (short)f2bf(v - bf2f(h));
        }
      }
      #pragma unroll
      for (int rr = 0; rr < 4; ++rr) {
        int r = rbase + rr;
        int sl = kseg ^ (r & 7);
        *(short8*)&sA[0][r * 64 + sl * 8] = vh[rr];
        if (NSEG == 3) *(short8*)&sA[1][r * 64 + sl * 8] = vl[rr];
      }
    }
    __syncthreads();
    short8 ah[4][2], bh[4][2];
    #pragma unroll
    for (int m = 0; m < 4; ++m)
      #pragma unroll
      for (int kh = 0; kh < 2; ++kh) {
        int r = wm * 64 + m * 16 + fr;
        int ch = kh * 4 + fk;
        ah[m][kh] = *(const short8*)&sA[0][r * 64 + (ch ^ (r & 7)) * 8];
      }
    #pragma unroll
    for (int nn = 0; nn < 4; ++nn)
      #pragma unroll
      for (int kh = 0; kh < 2; ++kh) {
        int nr = wn * 64 + nn * 16 + fr;
        int ch = kh * 4 + fk;
        bh[nn][kh] = *(const short8*)&sB[0][nr * 64 + (ch ^ (nr & 7)) * 8];
      }
    #pragma unroll
    for (int m = 0; m < 4; ++m)
      #pragma unroll
      for (int nn = 0; nn < 4; ++nn)
        #pragma unroll
        for (int kh = 0; kh < 2; ++kh)
          acc[m][nn] = __builtin_amdgcn_mfma_f32_16x16x32_bf16(
              ah[m][kh], bh[nn][kh], acc[m][nn], 0, 0, 0);
    if (NSEG == 3) {
      short8 bl[4][2];
      #pragma unroll
      for (int nn = 0; nn < 4; ++nn)
        #pragma unroll
        for (int kh = 0; kh < 2; ++kh) {
          int nr = wn * 64 + nn * 16 + fr;
          int ch = kh * 4 + fk;
          bl[nn][kh] = *(const short8*)&sB[1][nr * 64 + (ch ^ (nr & 7)) * 8];
        }
      #pragma unroll
      for (int m = 0; m < 4; ++m)
        #pragma unroll
        for (int nn = 0; nn < 4; ++nn)
          #pragma unroll
          for (int kh = 0; kh < 2; ++kh)
            acc[m][nn] = __builtin_amdgcn_mfma_f32_16x16x32_bf16(
                ah[m][kh], bl[nn][kh], acc[m][nn], 0, 0, 0);
      short8 al[4][2];
      #pragma unroll
      for (int m = 0; m < 4; ++m)
        #pragma unroll
        for (int kh = 0; kh < 2; ++kh) {
          int r = wm * 64 + m * 16 + fr;
          int ch = kh * 4 + fk;
          al[m][kh] = *(const short8*)&sA[1][r * 64 + (ch ^ (r & 7)) * 8];
        }
      #pragma unroll
      for (int m = 0; m < 4; ++m)
        #pragma unroll
        for (int nn = 0; nn < 4; ++nn)
          #pragma unroll
          for (int kh = 0; kh < 2; ++kh)
            acc[m][nn] = __builtin_amdgcn_mfma_f32_16x16x32_bf16(
                al[m][kh], bh[nn][kh], acc[m][nn], 0, 0, 0);
    }
  }

  #pragma unroll
  for (int m = 0; m < 4; ++m) {
    #pragma unroll
    for (int nn = 0; nn < 4; ++nn) {
      f32x4 a = acc[m][nn];
      int colL = wn * 64 + nn * 16 + fr;
      int col = ct * 128 + colL;
      float b2v = sb2[colL];
      #pragma unroll
      for (int g = 0; g < 4; ++g) {
        int r = wm * 64 + m * 16 + fk * 4 + g;
        int ent = sent[r];
        if (ent >= 0) {
          float* p = yacc + ((size_t)(ent >> 1)) * 1024 + col;
          *p += sw_[r] * (a[g] + b2v);
        }
      }
    }
  }
}

// ---------------------------------------------------------------------------
// LayerNorm (two-pass), in-place capable (yacc == out).
// ---------------------------------------------------------------------------
__global__ __launch_bounds__(256) void k_ln(
    const float* __restrict__ yacc, const float* __restrict__ g,
    const float* __restrict__ bta, float* __restrict__ out) {
  int t = blockIdx.x, tid = threadIdx.x;
  const float4* yr = (const float4*)(yacc + (size_t)t * DDIM);
  float4 y = yr[tid];
  float s = y.x + y.y + y.z + y.w;
  #pragma unroll
  for (int off = 32; off; off >>= 1) s += __shfl_xor(s, off);
  __shared__ float red1[4], red2[4];
  int wave = tid >> 6, lane = tid & 63;
  if (lane == 0) red1[wave] = s;
  __syncthreads();
  float mu = (red1[0]+red1[1]+red1[2]+red1[3]) * (1.f/(float)DDIM);
  float ax = y.x - mu, ay = y.y - mu, az = y.z - mu, aw = y.w - mu;
  float sq = ax*ax + ay*ay + az*az + aw*aw;
  #pragma unroll
  for (int off = 32; off; off >>= 1) sq += __shfl_xor(sq, off);
  if (lane == 0) red2[wave] = sq;
  __syncthreads();
  float var = (red2[0]+red2[1]+red2[2]+red2[3]) * (1.f/(float)DDIM);
  float rs = 1.f / sqrtf(var + 1e-5f);
  float4 gv = ((const float4*)g)[tid];
  float4 bv = ((const float4*)bta)[tid];
  float4 o;
  o.x = ax*rs*gv.x + bv.x;
  o.y = ay*rs*gv.y + bv.y;
  o.z = az*rs*gv.z + bv.z;
  o.w = aw*rs*gv.w + bv.w;
  ((float4*)(out + (size_t)t * DDIM))[tid] = o;
}

// ---------------------------------------------------------------------------
extern "C" void kernel_launch(void* const* d_in, const int* in_sizes, int n_in,
                              void* d_out, int out_size, void* d_ws, size_t ws_size,
                              hipStream_t stream) {
  const float* x   = (const float*)d_in[0];
  const float* gW  = (const float*)d_in[1];
  const float* gb  = (const float*)d_in[2];
  const float* qp  = (const float*)d_in[3];
  const float* rW  = (const float*)d_in[4];
  const float* rb  = (const float*)d_in[5];
  const float* w2  = (const float*)d_in[6];
  const float* b2  = (const float*)d_in[7];
  const float* lg  = (const float*)d_in[8];
  const float* lb  = (const float*)d_in[9];
  float* out = (float*)d_out;     // doubles as yacc (residual accumulator)

  char* ws = (char*)d_ws;
  unsigned short* whiT = (unsigned short*)ws;                       // 16MB
  unsigned short* wloT = (unsigned short*)(ws + 16777216);          // 16MB
  float* q8   = (float*)(ws + 33554432);                            // 512KB
  float* selw = (float*)(ws + 34078720);                            // 64KB
  int* listA  = (int*)(ws + 34144256);                              // 256KB
  int* listB  = (int*)(ws + 34406400);                              // 256KB
  int* cntA   = (int*)(ws + 34668544);                              // 32B
  int* cntB   = (int*)(ws + 34668576);                              // 32B

  // block-0 w2 -> bf16 hi/lo transposed
  k_wconv<true><<<dim3(16, 16, 8), 256, 0, stream>>>(w2, whiT, wloT);

  for (int blk = 0; blk < NB; ++blk) {
    const float* xin = blk ? (const float*)out : x;
    hipMemsetAsync(cntA, 0, 64, stream);   // cntA+cntB adjacent
    k_gate<<<dim3(BTOK/4), 256, 0, stream>>>(
        xin, gW + (size_t)blk * DDIM * NEXP, gb + (size_t)blk * NEXP,
        selw, cntA, cntB, listA, listB, out);
    k_qsim<<<dim3(128, NEXP, 2), 256, 0, stream>>>(
        xin, qp + (size_t)blk * NEXP * NL * NQ * 3, listA, listB, cntA, cntB, q8);
    const float* rWb = rW + (size_t)blk * NEXP * NQ * HDIM;
    const float* rbb = rb + (size_t)blk * NEXP * HDIM;
    const float* b2b = b2 + (size_t)blk * NEXP * DDIM;
    if (blk == 0) {
      k_gemm<3><<<dim3(64, 64), 256, 0, stream>>>(
          q8, rWb, rbb, whiT, wloT, b2b, listA, cntA, selw, out);
      k_gemm<3><<<dim3(64, 64), 256, 0, stream>>>(
          q8, rWb, rbb, whiT, wloT, b2b, listB, cntB, selw, out);
      k_wconv<false><<<dim3(16, 16, 8), 256, 0, stream>>>(
          w2 + (size_t)NEXP * HDIM * DDIM, whiT, wloT);
    } else {
      k_gemm<1><<<dim3(64, 64), 256, 0, stream>>>(
          q8, rWb, rbb, whiT, wloT, b2b, listA, cntA, selw, out);
      k_gemm<1><<<dim3(64, 64), 256, 0, stream>>>(
          q8, rWb, rbb, whiT, wloT, b2b, listB, cntB, selw, out);
    }
    k_ln<<<dim3(BTOK), 256, 0, stream>>>(
        out, lg + (size_t)blk * DDIM, lb + (size_t)blk * DDIM, out);
  }
}

// Round 5
// 996.977 us; speedup vs baseline: 2.7476x; 1.1993x over previous
//
#include <hip/hip_runtime.h>
#include <hip/hip_bf16.h>

#define NB    2
#define BTOK  8192
#define DDIM  1024
#define HDIM  1024
#define NEXP  8
#define NQ    8
#define NL    2

typedef __attribute__((ext_vector_type(8))) short short8;
typedef __attribute__((ext_vector_type(4))) float f32x4;

__device__ __forceinline__ unsigned short f2bf(float v) {
  union { __hip_bfloat16 b; unsigned short u; } cv;
  cv.b = __float2bfloat16(v);
  return cv.u;
}
__device__ __forceinline__ float bf2f(unsigned short u) {
  union { unsigned short u; __hip_bfloat16 b; } cv;
  cv.u = u;
  return __bfloat162float(cv.b);
}

__device__ __forceinline__ void gload_lds16(const void* g, void* l) {
  __builtin_amdgcn_global_load_lds(
      (const __attribute__((address_space(1))) unsigned int*)g,
      (__attribute__((address_space(3))) unsigned int*)l, 16, 0, 0);
}

// ---------------------------------------------------------------------------
// Gate (LDS-free): logits = x@gW + gb, softmax, top-2 (strict > = lowest
// index ties), weights = softmax over the two top PROBS.
// Wave handles 4 tokens: per chunk c, lane holds gW row (c*64+lane) in 8
// regs (32B coalesced L2 load), FMAs vs 4 coalesced scalar x reads.
// Butterfly-reduce 32 accs; lanes 0..3 finalize one token each.
// No yacc write -- slot-A GEMM epilogue seeds yacc = x + w*out.
// ---------------------------------------------------------------------------
__global__ __launch_bounds__(256) void k_gate(
    const float* __restrict__ xin, const float* __restrict__ gW,
    const float* __restrict__ gb, float* __restrict__ selw,
    int* __restrict__ cntA, int* __restrict__ cntB,
    int* __restrict__ listA, int* __restrict__ listB) {
  int tid = threadIdx.x, wave = tid >> 6, lane = tid & 63;
  int t0 = blockIdx.x * 16 + wave * 4;
  const float* xp = xin + (size_t)t0 * DDIM;

  float acc[4][8];
  #pragma unroll
  for (int tt = 0; tt < 4; ++tt)
    #pragma unroll
    for (int e = 0; e < 8; ++e) acc[tt][e] = 0.f;

  #pragma unroll
  for (int c = 0; c < 16; ++c) {
    int d = c * 64 + lane;
    float4 g0 = *(const float4*)&gW[(size_t)d * 8];
    float4 g1 = *(const float4*)&gW[(size_t)d * 8 + 4];
    #pragma unroll
    for (int tt = 0; tt < 4; ++tt) {
      float xv = xp[(size_t)tt * DDIM + d];
      acc[tt][0] += xv * g0.x; acc[tt][1] += xv * g0.y;
      acc[tt][2] += xv * g0.z; acc[tt][3] += xv * g0.w;
      acc[tt][4] += xv * g1.x; acc[tt][5] += xv * g1.y;
      acc[tt][6] += xv * g1.z; acc[tt][7] += xv * g1.w;
    }
  }

  #pragma unroll
  for (int tt = 0; tt < 4; ++tt)
    #pragma unroll
    for (int e = 0; e < 8; ++e) {
      float v = acc[tt][e];
      #pragma unroll
      for (int off = 32; off; off >>= 1) v += __shfl_xor(v, off);
      acc[tt][e] = v;
    }

  if (lane < 4) {
    int t = t0 + lane;
    float p[8];
    #pragma unroll
    for (int e = 0; e < 8; ++e) {
      float v = acc[0][e];
      v = (lane == 1) ? acc[1][e] : v;
      v = (lane == 2) ? acc[2][e] : v;
      v = (lane == 3) ? acc[3][e] : v;
      p[e] = v + gb[e];
    }
    float m = -3.4e38f;
    #pragma unroll
    for (int e = 0; e < 8; ++e) m = fmaxf(m, p[e]);
    float s = 0.f;
    #pragma unroll
    for (int e = 0; e < 8; ++e) { p[e] = expf(p[e] - m); s += p[e]; }
    float inv = 1.f / s;
    #pragma unroll
    for (int e = 0; e < 8; ++e) p[e] *= inv;
    int i1 = 0;
    #pragma unroll
    for (int e = 1; e < 8; ++e) if (p[e] > p[i1]) i1 = e;
    int i2 = (i1 == 0) ? 1 : 0;
    #pragma unroll
    for (int e = 0; e < 8; ++e)
      if (e != i1 && e != i2 && p[e] > p[i2]) i2 = e;
    float pa = p[i1], pb = p[i2];
    float eb = expf(pb - pa);
    float wa = 1.f / (1.f + eb);
    float wb = eb * wa;
    int t2 = t * 2;
    selw[t2]   = wa;
    selw[t2+1] = wb;
    int pos1 = atomicAdd(&cntA[i1], 1);
    listA[i1 * BTOK + pos1] = t2;
    int pos2 = atomicAdd(&cntB[i2], 1);
    listB[i2 * BTOK + pos2] = t2 + 1;
  }
}

// ---------------------------------------------------------------------------
// Register-resident quantum sim (verified round 4): 4 lanes per
// (token,expert), 64 complex amps per lane, zero LDS, zero barriers.
// ---------------------------------------------------------------------------
__global__ __launch_bounds__(256, 1) void k_qsim(
    const float* __restrict__ xin, const float* __restrict__ qp,
    const int* __restrict__ listA, const int* __restrict__ listB,
    const int* __restrict__ cntA, const int* __restrict__ cntB,
    float* __restrict__ q8) {
  int slot = blockIdx.z;
  const int* list = slot ? listB : listA;
  const int* cnt  = slot ? cntB  : cntA;
  int e = blockIdx.y;
  int tid = threadIdx.x;
  int grp = tid >> 2, sub = tid & 3;
  int pos = blockIdx.x * 64 + grp;
  if (pos >= cnt[e]) return;
  int ent = list[e * BTOK + pos];
  int t = ent >> 1;
  int sub0 = sub & 1, sub1 = sub >> 1;

  // layer-0 rotated per-qubit 2-vectors v = Rot @ [cos(a/2), sin(a/2)]
  float v0r[8], v0i[8], v1r[8], v1i[8];
  {
    const float* qp0 = qp + (size_t)e * (NL * NQ * 3);
    float4 a0 = *(const float4*)(xin + (size_t)t * DDIM);
    float4 a1 = *(const float4*)(xin + (size_t)t * DDIM + 4);
    float aa[8] = {a0.x,a0.y,a0.z,a0.w,a1.x,a1.y,a1.z,a1.w};
    #pragma unroll
    for (int q = 0; q < 8; ++q) {
      float a   = aa[q];
      float phi = qp0[q*3+0], th = qp0[q*3+1], om = qp0[q*3+2];
      float sa, ca;  sincosf(0.5f * a, &sa, &ca);
      float s,  c;   sincosf(0.5f * th, &s, &c);
      float sp, cp;  sincosf(0.5f * (phi + om), &sp, &cp);
      float sq_, cq_; sincosf(0.5f * (phi - om), &sq_, &cq_);
      v0r[q] =  c*cp*ca - s*cq_*sa;
      v0i[q] = -c*sp*ca - s*sq_*sa;
      v1r[q] =  s*cq_*ca + c*cp*sa;
      v1i[q] = -s*sq_*ca + c*sp*sa;
    }
  }

  // product build into 64 register amps (fully compile-time indexed)
  float ar[64], ai[64];
  {
    int s01 = sub0 ^ sub1;
    float f0r = sub1 ? v1r[0] : v0r[0], f0i = sub1 ? v1i[0] : v0i[0];
    float f1r = s01  ? v1r[1] : v0r[1], f1i = s01  ? v1i[1] : v0i[1];
    float Pr = f0r*f1r - f0i*f1i, Pi = f0r*f1i + f0i*f1r;
    float b0r = sub0 ? v1r[2] : v0r[2], b0i = sub0 ? v1i[2] : v0i[2];
    float b1r = sub0 ? v0r[2] : v1r[2], b1i = sub0 ? v0i[2] : v1i[2];
    ar[0]  = Pr*b0r - Pi*b0i;  ai[0]  = Pr*b0i + Pi*b0r;   // l5 = 0
    ar[32] = Pr*b1r - Pi*b1i;  ai[32] = Pr*b1i + Pi*b1r;   // l5 = 1
    #pragma unroll
    for (int lev = 0; lev < 5; ++lev) {       // qubit 3+lev, bit k = 4-lev
      const int k = 4 - lev;
      const int np = 2 << lev;
      #pragma unroll
      for (int m = np - 1; m >= 0; --m) {
        const int p = m << (k + 1);
        const int prevb = m & 1;              // bit k+1 of p
        const int q = 3 + lev;
        float pr = ar[p], pj = ai[p];
        float s0r = prevb ? v1r[q] : v0r[q], s0i = prevb ? v1i[q] : v0i[q];
        float s1r = prevb ? v0r[q] : v1r[q], s1i = prevb ? v0i[q] : v1i[q];
        ar[p | (1 << k)] = pr*s1r - pj*s1i;
        ai[p | (1 << k)] = pr*s1i + pj*s1r;
        ar[p]            = pr*s0r - pj*s0i;
        ai[p]            = pr*s0i + pj*s0r;
      }
    }
  }

  // layer-1 Rot gates
  const float* qp1 = qp + (size_t)e * (NL * NQ * 3) + NQ * 3;
  #pragma unroll
  for (int qq = 2; qq < 8; ++qq) {
    float phi = qp1[qq*3+0], th = qp1[qq*3+1], om = qp1[qq*3+2];
    float s,  c;   sincosf(0.5f * th, &s, &c);
    float sp, cp;  sincosf(0.5f * (phi + om), &sp, &cp);
    float sq_, cq_; sincosf(0.5f * (phi - om), &sq_, &cq_);
    float M00r =  c*cp,  M00i = -c*sp;
    float M01r = -s*cq_, M01i = -s*sq_;
    float M10r =  s*cq_, M10i = -s*sq_;
    float M11r =  c*cp,  M11i =  c*sp;
    const int bm = 1 << (7 - qq);
    #pragma unroll
    for (int pp = 0; pp < 32; ++pp) {
      const int i0 = ((pp & ~(bm - 1)) << 1) | (pp & (bm - 1));
      const int i1 = i0 | bm;
      float a0r = ar[i0], a0i = ai[i0], a1r = ar[i1], a1i = ai[i1];
      ar[i0] = M00r*a0r - M00i*a0i + M01r*a1r - M01i*a1i;
      ai[i0] = M00r*a0i + M00i*a0r + M01r*a1i + M01i*a1r;
      ar[i1] = M10r*a0r - M10i*a0i + M11r*a1r - M11i*a1i;
      ai[i1] = M10r*a0i + M10i*a0r + M11r*a1i + M11i*a1r;
    }
  }
  // qubit 1 (lane mask 1, high = sub0) then qubit 0 (mask 2, high = sub1)
  #pragma unroll
  for (int g = 0; g < 2; ++g) {
    const int qq = 1 - g;
    const int mask = g ? 2 : 1;
    int high = g ? sub1 : sub0;
    float phi = qp1[qq*3+0], th = qp1[qq*3+1], om = qp1[qq*3+2];
    float s,  c;   sincosf(0.5f * th, &s, &c);
    float sp, cp;  sincosf(0.5f * (phi + om), &sp, &cp);
    float sq_, cq_; sincosf(0.5f * (phi - om), &sq_, &cq_);
    float M00r =  c*cp,  M00i = -c*sp;
    float M01r = -s*cq_, M01i = -s*sq_;
    float M10r =  s*cq_, M10i = -s*sq_;
    float M11r =  c*cp,  M11i =  c*sp;
    float CL0r = high ? M10r : M00r, CL0i = high ? M10i : M00i;
    float CL1r = high ? M11r : M01r, CL1i = high ? M11i : M01i;
    #pragma unroll
    for (int l = 0; l < 64; ++l) {
      float pr = ar[l], pj = ai[l];
      float or_ = __shfl_xor(pr, mask);
      float oi_ = __shfl_xor(pj, mask);
      float a0r = high ? or_ : pr, a0i = high ? oi_ : pj;
      float a1r = high ? pr : or_, a1i = high ? pj : oi_;
      ar[l] = CL0r*a0r - CL0i*a0i + CL1r*a1r - CL1i*a1i;
      ai[l] = CL0r*a0i + CL0i*a0r + CL1r*a1i + CL1i*a1r;
    }
  }

  // readout with CNOT-chain-2 folded into signs
  float S = 0.f, zt0=0.f, zt1=0.f, zt2=0.f, zt3=0.f, zt4=0.f, zt5=0.f;
  #pragma unroll
  for (int l = 0; l < 64; ++l) {
    float pb = ar[l]*ar[l] + ai[l]*ai[l];
    S += pb;
    zt0 += (__builtin_popcount(l >> 5) & 1) ? -pb : pb;
    zt1 += (__builtin_popcount(l >> 4) & 1) ? -pb : pb;
    zt2 += (__builtin_popcount(l >> 3) & 1) ? -pb : pb;
    zt3 += (__builtin_popcount(l >> 2) & 1) ? -pb : pb;
    zt4 += (__builtin_popcount(l >> 1) & 1) ? -pb : pb;
    zt5 += (__builtin_popcount(l) & 1) ? -pb : pb;
  }
  int cc = sub0 ^ sub1;
  float sgnc = cc ? -1.f : 1.f;
  float z0 = sub1 ? -S : S;
  float z1 = cc ? -S : S;
  float z2 = sgnc*zt0, z3 = sgnc*zt1, z4 = sgnc*zt2;
  float z5 = sgnc*zt3, z6 = sgnc*zt4, z7 = sgnc*zt5;
  z0 += __shfl_xor(z0,1); z0 += __shfl_xor(z0,2);
  z1 += __shfl_xor(z1,1); z1 += __shfl_xor(z1,2);
  z2 += __shfl_xor(z2,1); z2 += __shfl_xor(z2,2);
  z3 += __shfl_xor(z3,1); z3 += __shfl_xor(z3,2);
  z4 += __shfl_xor(z4,1); z4 += __shfl_xor(z4,2);
  z5 += __shfl_xor(z5,1); z5 += __shfl_xor(z5,2);
  z6 += __shfl_xor(z6,1); z6 += __shfl_xor(z6,2);
  z7 += __shfl_xor(z7,1); z7 += __shfl_xor(z7,2);
  float w0 = z0, w1 = z1;
  if (sub == 1)      { w0 = z2; w1 = z3; }
  else if (sub == 2) { w0 = z4; w1 = z5; }
  else if (sub == 3) { w0 = z6; w1 = z7; }
  *(float2*)(q8 + (size_t)ent * 8 + sub * 2) = make_float2(w0, w1);
}

// ---------------------------------------------------------------------------
// w2 convert (+transpose): w2[e][k][n] fp32 -> whiT[e][n][k] bf16 (and
// wloT = bf16(w2 - hi) when LO).
// ---------------------------------------------------------------------------
template<bool LO>
__global__ __launch_bounds__(256) void k_wconv(
    const float* __restrict__ w2, unsigned short* __restrict__ whiT,
    unsigned short* __restrict__ wloT) {
  __shared__ float tile[64][68];
  int e = blockIdx.z, kt = blockIdx.x, nt = blockIdx.y;
  const float* src = w2 + ((size_t)e * 1024 + kt * 64) * 1024 + nt * 64;
  int tid = threadIdx.x;
  int jr = (tid & 15) * 4;
  int ir = tid >> 4;
  #pragma unroll
  for (int p = 0; p < 4; ++p) {
    float4 v = *(const float4*)&src[(size_t)(ir + p*16) * 1024 + jr];
    *(float4*)&tile[ir + p*16][jr] = v;
  }
  __syncthreads();
  int nl_ = tid >> 2;
  int kc = (tid & 3) * 16;
  short8 hi0, hi1, lo0, lo1;
  #pragma unroll
  for (int i = 0; i < 8; ++i) {
    float v = tile[kc + i][nl_];
    unsigned short h = f2bf(v);
    hi0[i] = (short)h;
    if (LO) lo0[i] = (short)f2bf(v - bf2f(h));
  }
  #pragma unroll
  for (int i = 0; i < 8; ++i) {
    float v = tile[kc + 8 + i][nl_];
    unsigned short h = f2bf(v);
    hi1[i] = (short)h;
    if (LO) lo1[i] = (short)f2bf(v - bf2f(h));
  }
  size_t orow = ((size_t)e * 1024 + nt * 64 + nl_) * 1024 + kt * 64 + kc;
  *(short8*)&whiT[orow]     = hi0;
  *(short8*)&whiT[orow + 8] = hi1;
  if (LO) {
    *(short8*)&wloT[orow]     = lo0;
    *(short8*)&wloT[orow + 8] = lo1;
  }
}

// ---------------------------------------------------------------------------
// MFMA expert MLP over one slot's entry lists.
// INIT (slot A): yacc[t] = x[t] + w*(h@w2 + b2)   (seeds residual)
// else (slot B): yacc[t] += w*(h@w2 + b2)
// ---------------------------------------------------------------------------
template<int NSEG, bool INIT>
__global__ __launch_bounds__(256, 2) void k_gemm(
    const float* __restrict__ xin, const float* __restrict__ q8,
    const float* __restrict__ rW, const float* __restrict__ rb,
    const unsigned short* __restrict__ whiT,
    const unsigned short* __restrict__ wloT, const float* __restrict__ b2,
    const int* __restrict__ list, const int* __restrict__ cnt,
    const float* __restrict__ selw, float* __restrict__ yacc) {
  constexpr int NA = (NSEG == 3) ? 2 : 1;
  int bx = blockIdx.x;
  int e = bx >> 3, ct = bx & 7, rt = blockIdx.y;
  int n = cnt[e];
  int r0 = rt * 128;
  if (r0 >= n) return;

  __shared__ unsigned short sA[NA][128 * 64];
  __shared__ unsigned short sB[NA][128 * 64];
  __shared__ float srWt[2][64][8];
  __shared__ float srb[2][64];
  __shared__ int   sent[128];
  __shared__ float sw_[128];
  __shared__ float sb2[128];

  int tid = threadIdx.x;
  int wave = tid >> 6, lane = tid & 63;
  int rbase = (tid & 31) * 4;
  int kseg = tid >> 5;

  const float* rWe = rW + (size_t)e * 8 * 1024;

  float q[4][8];
  #pragma unroll
  for (int rr = 0; rr < 4; ++rr) {
    int r = r0 + rbase + rr;
    if (r < n) {
      int ent = list[e * BTOK + r];
      const float* qp_ = q8 + (size_t)ent * 8;
      float4 a = *(const float4*)qp_;
      float4 b = *(const float4*)(qp_ + 4);
      q[rr][0]=a.x; q[rr][1]=a.y; q[rr][2]=a.z; q[rr][3]=a.w;
      q[rr][4]=b.x; q[rr][5]=b.y; q[rr][6]=b.z; q[rr][7]=b.w;
    } else {
      #pragma unroll
      for (int j = 0; j < 8; ++j) q[rr][j] = 0.f;
    }
  }
  if (tid < 128) {
    int r = r0 + tid;
    int ent = (r < n) ? list[e * BTOK + r] : -1;
    sent[tid] = ent;
    sw_[tid] = (ent >= 0) ? selw[ent] : 0.f;
    sb2[tid] = b2[(size_t)e * 1024 + ct * 128 + tid];
  }
  {
    int j = tid & 7, kk = tid >> 3;
    srWt[0][kk][j]      = rWe[j * 1024 + kk];
    srWt[0][kk + 32][j] = rWe[j * 1024 + kk + 32];
  }
  if (tid < 64) srb[0][tid] = rb[(size_t)e * 1024 + tid];

  f32x4 acc[4][4];
  #pragma unroll
  for (int m = 0; m < 4; ++m)
    #pragma unroll
    for (int nn = 0; nn < 4; ++nn)
      acc[m][nn] = (f32x4){0.f, 0.f, 0.f, 0.f};

  const unsigned short* Bh0 = whiT + ((size_t)(e * 1024 + ct * 128)) * 1024;
  const unsigned short* Bl0 = (NSEG == 3)
      ? wloT + ((size_t)(e * 1024 + ct * 128)) * 1024 : Bh0;

  int wm = wave >> 1, wn = wave & 1;
  int fr = lane & 15, fk = lane >> 4;

  for (int ks = 0; ks < 16; ++ks) {
    int buf = ks & 1;
    __syncthreads();
    #pragma unroll
    for (int s = 0; s < NA; ++s) {
      const unsigned short* bsrc = (s ? Bl0 : Bh0) + ks * 64;
      #pragma unroll
      for (int i = 0; i < 4; ++i) {
        int slotbase = (wave * 4 + i) * 64;
        int slot = slotbase + lane;
        int nrow = slot >> 3, c = slot & 7;
        const unsigned short* g = bsrc + (size_t)nrow * 1024 + ((c ^ (nrow & 7)) << 3);
        gload_lds16(g, &sB[s][slotbase * 8]);
      }
    }
    if (ks + 1 < 16) {
      int j = tid & 7, kk = tid >> 3;
      srWt[buf ^ 1][kk][j]      = rWe[j * 1024 + (ks + 1) * 64 + kk];
      srWt[buf ^ 1][kk + 32][j] = rWe[j * 1024 + (ks + 1) * 64 + kk + 32];
      if (tid < 64) srb[buf ^ 1][tid] = rb[(size_t)e * 1024 + (ks + 1) * 64 + tid];
    }
    {
      short8 vh[4], vl[4];
      #pragma unroll
      for (int kk8 = 0; kk8 < 8; ++kk8) {
        int kk = kseg * 8 + kk8;
        float4 w0 = *(const float4*)&srWt[buf][kk][0];
        float4 w1 = *(const float4*)&srWt[buf][kk][4];
        float rbv = srb[buf][kk];
        #pragma unroll
        for (int rr = 0; rr < 4; ++rr) {
          float v = rbv + q[rr][0]*w0.x + q[rr][1]*w0.y + q[rr][2]*w0.z + q[rr][3]*w0.w
                        + q[rr][4]*w1.x + q[rr][5]*w1.y + q[rr][6]*w1.z + q[rr][7]*w1.w;
          v = fmaxf(v, 0.f);
          unsigned short h = f2bf(v);
          vh[rr][kk8] = (short)h;
          if (NSEG == 3) vl[rr][kk8] = (short)f2bf(v - bf2f(h));
        }
      }
      #pragma unroll
      for (int rr = 0; rr < 4; ++rr) {
        int r = rbase + rr;
        int sl = kseg ^ (r & 7);
        *(short8*)&sA[0][r * 64 + sl * 8] = vh[rr];
        if (NSEG == 3) *(short8*)&sA[1][r * 64 + sl * 8] = vl[rr];
      }
    }
    __syncthreads();
    short8 ah[4][2], bh[4][2];
    #pragma unroll
    for (int m = 0; m < 4; ++m)
      #pragma unroll
      for (int kh = 0; kh < 2; ++kh) {
        int r = wm * 64 + m * 16 + fr;
        int ch = kh * 4 + fk;
        ah[m][kh] = *(const short8*)&sA[0][r * 64 + (ch ^ (r & 7)) * 8];
      }
    #pragma unroll
    for (int nn = 0; nn < 4; ++nn)
      #pragma unroll
      for (int kh = 0; kh < 2; ++kh) {
        int nr = wn * 64 + nn * 16 + fr;
        int ch = kh * 4 + fk;
        bh[nn][kh] = *(const short8*)&sB[0][nr * 64 + (ch ^ (nr & 7)) * 8];
      }
    #pragma unroll
    for (int m = 0; m < 4; ++m)
      #pragma unroll
      for (int nn = 0; nn < 4; ++nn)
        #pragma unroll
        for (int kh = 0; kh < 2; ++kh)
          acc[m][nn] = __builtin_amdgcn_mfma_f32_16x16x32_bf16(
              ah[m][kh], bh[nn][kh], acc[m][nn], 0, 0, 0);
    if (NSEG == 3) {
      short8 bl[4][2];
      #pragma unroll
      for (int nn = 0; nn < 4; ++nn)
        #pragma unroll
        for (int kh = 0; kh < 2; ++kh) {
          int nr = wn * 64 + nn * 16 + fr;
          int ch = kh * 4 + fk;
          bl[nn][kh] = *(const short8*)&sB[1][nr * 64 + (ch ^ (nr & 7)) * 8];
        }
      #pragma unroll
      for (int m = 0; m < 4; ++m)
        #pragma unroll
        for (int nn = 0; nn < 4; ++nn)
          #pragma unroll
          for (int kh = 0; kh < 2; ++kh)
            acc[m][nn] = __builtin_amdgcn_mfma_f32_16x16x32_bf16(
                ah[m][kh], bl[nn][kh], acc[m][nn], 0, 0, 0);
      short8 al[4][2];
      #pragma unroll
      for (int m = 0; m < 4; ++m)
        #pragma unroll
        for (int kh = 0; kh < 2; ++kh) {
          int r = wm * 64 + m * 16 + fr;
          int ch = kh * 4 + fk;
          al[m][kh] = *(const short8*)&sA[1][r * 64 + (ch ^ (r & 7)) * 8];
        }
      #pragma unroll
      for (int m = 0; m < 4; ++m)
        #pragma unroll
        for (int nn = 0; nn < 4; ++nn)
          #pragma unroll
          for (int kh = 0; kh < 2; ++kh)
            acc[m][nn] = __builtin_amdgcn_mfma_f32_16x16x32_bf16(
                al[m][kh], bh[nn][kh], acc[m][nn], 0, 0, 0);
    }
  }

  #pragma unroll
  for (int m = 0; m < 4; ++m) {
    #pragma unroll
    for (int nn = 0; nn < 4; ++nn) {
      f32x4 a = acc[m][nn];
      int colL = wn * 64 + nn * 16 + fr;
      int col = ct * 128 + colL;
      float b2v = sb2[colL];
      #pragma unroll
      for (int g = 0; g < 4; ++g) {
        int r = wm * 64 + m * 16 + fk * 4 + g;
        int ent = sent[r];
        if (ent >= 0) {
          size_t off = ((size_t)(ent >> 1)) * 1024 + col;
          float v = sw_[r] * (a[g] + b2v);
          if (INIT) yacc[off] = xin[off] + v;
          else      yacc[off] += v;
        }
      }
    }
  }
}

// ---------------------------------------------------------------------------
// LayerNorm (two-pass), in-place capable (yacc == out).
// ---------------------------------------------------------------------------
__global__ __launch_bounds__(256) void k_ln(
    const float* __restrict__ yacc, const float* __restrict__ g,
    const float* __restrict__ bta, float* __restrict__ out) {
  int t = blockIdx.x, tid = threadIdx.x;
  const float4* yr = (const float4*)(yacc + (size_t)t * DDIM);
  float4 y = yr[tid];
  float s = y.x + y.y + y.z + y.w;
  #pragma unroll
  for (int off = 32; off; off >>= 1) s += __shfl_xor(s, off);
  __shared__ float red1[4], red2[4];
  int wave = tid >> 6, lane = tid & 63;
  if (lane == 0) red1[wave] = s;
  __syncthreads();
  float mu = (red1[0]+red1[1]+red1[2]+red1[3]) * (1.f/(float)DDIM);
  float ax = y.x - mu, ay = y.y - mu, az = y.z - mu, aw = y.w - mu;
  float sq = ax*ax + ay*ay + az*az + aw*aw;
  #pragma unroll
  for (int off = 32; off; off >>= 1) sq += __shfl_xor(sq, off);
  if (lane == 0) red2[wave] = sq;
  __syncthreads();
  float var = (red2[0]+red2[1]+red2[2]+red2[3]) * (1.f/(float)DDIM);
  float rs = 1.f / sqrtf(var + 1e-5f);
  float4 gv = ((const float4*)g)[tid];
  float4 bv = ((const float4*)bta)[tid];
  float4 o;
  o.x = ax*rs*gv.x + bv.x;
  o.y = ay*rs*gv.y + bv.y;
  o.z = az*rs*gv.z + bv.z;
  o.w = aw*rs*gv.w + bv.w;
  ((float4*)(out + (size_t)t * DDIM))[tid] = o;
}

// ---------------------------------------------------------------------------
extern "C" void kernel_launch(void* const* d_in, const int* in_sizes, int n_in,
                              void* d_out, int out_size, void* d_ws, size_t ws_size,
                              hipStream_t stream) {
  const float* x   = (const float*)d_in[0];
  const float* gW  = (const float*)d_in[1];
  const float* gb  = (const float*)d_in[2];
  const float* qp  = (const float*)d_in[3];
  const float* rW  = (const float*)d_in[4];
  const float* rb  = (const float*)d_in[5];
  const float* w2  = (const float*)d_in[6];
  const float* b2  = (const float*)d_in[7];
  const float* lg  = (const float*)d_in[8];
  const float* lb  = (const float*)d_in[9];
  float* out = (float*)d_out;     // doubles as yacc (residual accumulator)

  char* ws = (char*)d_ws;
  unsigned short* whiT = (unsigned short*)ws;                       // 16MB
  unsigned short* wloT = (unsigned short*)(ws + 16777216);          // 16MB
  float* q8   = (float*)(ws + 33554432);                            // 512KB
  float* selw = (float*)(ws + 34078720);                            // 64KB
  int* listA  = (int*)(ws + 34144256);                              // 256KB
  int* listB  = (int*)(ws + 34406400);                              // 256KB
  int* cntA   = (int*)(ws + 34668544);                              // 32B
  int* cntB   = (int*)(ws + 34668576);                              // 32B

  // block-0 w2 -> bf16 hi/lo transposed
  k_wconv<true><<<dim3(16, 16, 8), 256, 0, stream>>>(w2, whiT, wloT);

  for (int blk = 0; blk < NB; ++blk) {
    const float* xin = blk ? (const float*)out : x;
    hipMemsetAsync(cntA, 0, 64, stream);   // cntA+cntB adjacent
    k_gate<<<dim3(BTOK/16), 256, 0, stream>>>(
        xin, gW + (size_t)blk * DDIM * NEXP, gb + (size_t)blk * NEXP,
        selw, cntA, cntB, listA, listB);
    k_qsim<<<dim3(128, NEXP, 2), 256, 0, stream>>>(
        xin, qp + (size_t)blk * NEXP * NL * NQ * 3, listA, listB, cntA, cntB, q8);
    const float* rWb = rW + (size_t)blk * NEXP * NQ * HDIM;
    const float* rbb = rb + (size_t)blk * NEXP * HDIM;
    const float* b2b = b2 + (size_t)blk * NEXP * DDIM;
    if (blk == 0) {
      k_gemm<3, true><<<dim3(64, 64), 256, 0, stream>>>(
          xin, q8, rWb, rbb, whiT, wloT, b2b, listA, cntA, selw, out);
      k_gemm<3, false><<<dim3(64, 64), 256, 0, stream>>>(
          xin, q8, rWb, rbb, whiT, wloT, b2b, listB, cntB, selw, out);
      k_wconv<false><<<dim3(16, 16, 8), 256, 0, stream>>>(
          w2 + (size_t)NEXP * HDIM * DDIM, whiT, wloT);
    } else {
      k_gemm<1, true><<<dim3(64, 64), 256, 0, stream>>>(
          xin, q8, rWb, rbb, whiT, wloT, b2b, listA, cntA, selw, out);
      k_gemm<1, false><<<dim3(64, 64), 256, 0, stream>>>(
          xin, q8, rWb, rbb, whiT, wloT, b2b, listB, cntB, selw, out);
    }
    k_ln<<<dim3(BTOK), 256, 0, stream>>>(
        out, lg + (size_t)blk * DDIM, lb + (size_t)blk * DDIM, out);
  }
}